// Round 4
// baseline (685.971 us; speedup 1.0000x reference)
//
#include <hip/hip_runtime.h>
#include <stdint.h>

#define BB 2
#define NN 512
#define ENF 128
#define EEF 64
#define FF 64
#define HH 8

// static scratch offsets (floats)
#define WS_NF    0        // [B*N*64]   = 65536
#define WS_Q     65536    // [B*N*8]    = 8192
#define WS_V     73728    // [B*N*64]   = 65536  (v = att_W@q * 1/sqrt(8))
#define WS_EW    139264   // [64*64]    = 4096   (f32 weights, fallback path)
#define WS_EB    143360   // [64]
#define WS_STATS 143424   // [B*N*2]    = 2048   (m, 1/S per node row)
#define WS_FLAG  145472   // [7] flags + 1 pad
#define WS_EWFH  145480   // [8 frag][64 lane][4 u32] bf16-hi B fragments = 4096
#define WS_EWFL  149576   // same, bf16-lo residual                      = 4096
#define WS_TOTAL 153672
// flag index: 0=edges 1=nodes 2=node_W 3=node_b 4=edge_W 5=edge_b 6=att_W

__device__ __align__(16) float g_ws[WS_TOTAL];

using short8  = __attribute__((ext_vector_type(8))) short;
using floatx4 = __attribute__((ext_vector_type(4))) float;

__device__ __forceinline__ float bf2f(uint16_t u) {
  return __uint_as_float(((uint32_t)u) << 16);
}
__device__ __forceinline__ uint16_t f2bf(float f) {   // RNE f32->bf16
  uint32_t u = __float_as_uint(f);
  return (uint16_t)((u + 0x7FFFu + ((u >> 16) & 1u)) >> 16);
}
__device__ __forceinline__ float load1(const void* p, size_t i, bool isf32) {
  return isf32 ? ((const float*)p)[i] : bf2f(((const uint16_t*)p)[i]);
}
__device__ __forceinline__ float elu(float x) {
  return x > 0.f ? x : expf(x) - 1.0f;
}

constexpr float INV_SQRT8 = 0.35355339059327373f;

// ------------- K0: per-array dtype detection (f32 vs bf16 in memory) -------------
__global__ __launch_bounds__(256) void k0_detect(
    const uint16_t* p0, int c0, const uint16_t* p1, int c1,
    const uint16_t* p2, int c2, const uint16_t* p3, int c3,
    const uint16_t* p4, int c4, const uint16_t* p5, int c5,
    const uint16_t* p6, int c6) {
  const uint16_t* ptrs[7] = {p0, p1, p2, p3, p4, p5, p6};
  const int cnts[7] = {c0, c1, c2, c3, c4, c5, c6};
  const int a = blockIdx.x;
  const uint16_t* e = ptrs[a];
  int S = cnts[a] / 2; if (S > 2048) S = 2048;
  const int t = threadIdx.x;
  int hi = 0, z0 = 0, nz1 = 0;
  for (int i = t; i < S; i += 256) {
    uint16_t h0 = e[2 * i], h1 = e[2 * i + 1];
    if (((h0 >> 7) & 0xFF) >= 0x90) hi++;
    if (h0 == 0) z0++;
    if (h1 != 0) nz1++;
  }
  for (int o = 32; o > 0; o >>= 1) {
    hi += __shfl_xor(hi, o); z0 += __shfl_xor(z0, o); nz1 += __shfl_xor(nz1, o);
  }
  __shared__ int r[3][4];
  if ((t & 63) == 0) { int w = t >> 6; r[0][w] = hi; r[1][w] = z0; r[2][w] = nz1; }
  __syncthreads();
  if (t == 0) {
    int H  = r[0][0] + r[0][1] + r[0][2] + r[0][3];
    int Z  = r[1][0] + r[1][1] + r[1][2] + r[1][3];
    int NZ = r[2][0] + r[2][1] + r[2][2] + r[2][3];
    g_ws[WS_FLAG + a] =
        (H > S / 16 || (Z * 8 > S * 3 && NZ * 8 > S * 3)) ? 1.0f : 0.0f;
  }
}

// ---------------- K1: nf, q, v (+ upcast edge_W/edge_b, pack MFMA B-fragments) -----------
__global__ __launch_bounds__(64) void k1_nf_q_v(
    const void* __restrict__ nodes, const void* __restrict__ node_W,
    const void* __restrict__ node_b, const void* __restrict__ att_W,
    const void* __restrict__ edge_W, const void* __restrict__ edge_b) {
  float* nf  = g_ws + WS_NF;
  float* q   = g_ws + WS_Q;
  float* v   = g_ws + WS_V;
  float* eWf = g_ws + WS_EW;
  float* ebf = g_ws + WS_EB;
  const float* fl = g_ws + WS_FLAG;
  const bool fNodes = fl[1] != 0.f, fNW = fl[2] != 0.f, fNB = fl[3] != 0.f;
  const bool fEW = fl[4] != 0.f, fEB = fl[5] != 0.f, fAW = fl[6] != 0.f;
  const int bi = blockIdx.x;           // b*N + n
  const int t  = threadIdx.x;          // 0..63
  __shared__ float nd[ENF];
  __shared__ float nf_s[FF];
  __shared__ float q_s[HH];
  nd[t]      = load1(nodes, (size_t)bi * ENF + t, fNodes);
  nd[t + 64] = load1(nodes, (size_t)bi * ENF + t + 64, fNodes);
  __syncthreads();
  float acc = load1(node_b, t, fNB);
#pragma unroll 8
  for (int e = 0; e < ENF; ++e) acc += nd[e] * load1(node_W, e * FF + t, fNW);
  nf[bi * FF + t] = acc;
  nf_s[t] = acc;
  __syncthreads();
  if (t < HH) {
    float s = 0.f;
#pragma unroll
    for (int k = 0; k < FF; ++k) s += nf_s[k] * load1(att_W, k * HH + t, fAW);
    q[bi * HH + t] = s;
    q_s[t] = s;
  }
  __syncthreads();
  {
    float s = 0.f;
#pragma unroll
    for (int h = 0; h < HH; ++h) s += load1(att_W, t * HH + h, fAW) * q_s[h];
    v[bi * FF + t] = s * INV_SQRT8;    // fold 1/sqrt(D_EDGE)
  }
  if (bi == 0) {
    for (int idx = t; idx < EEF * FF; idx += 64)
      eWf[idx] = load1(edge_W, idx, fEW);
    ebf[t] = load1(edge_b, t, fEB);
    // ---- pack B fragments for mfma_f32_16x16x32_bf16, split-precision ----
    // B[k][n]: lane l holds k=(l>>4)*8+j (j=0..7), n=l&15; frag f = ks*4+nt.
    uint32_t* dH = (uint32_t*)(g_ws + WS_EWFH);
    uint32_t* dL = (uint32_t*)(g_ws + WS_EWFL);
#pragma unroll
    for (int ks = 0; ks < 2; ++ks) {
#pragma unroll
      for (int nt = 0; nt < 4; ++nt) {
        const int f = ks * 4 + nt;
        const int n = nt * 16 + (t & 15);
        const int e0 = ks * 32 + ((t >> 4) << 3);
#pragma unroll
        for (int jj = 0; jj < 4; ++jj) {
          float w0 = load1(edge_W, (size_t)(e0 + 2 * jj) * FF + n, fEW);
          float w1 = load1(edge_W, (size_t)(e0 + 2 * jj + 1) * FF + n, fEW);
          uint16_t h0 = f2bf(w0);
          uint16_t h1 = f2bf(w1);
          uint16_t l0 = f2bf(w0 - __uint_as_float((uint32_t)h0 << 16));
          uint16_t l1 = f2bf(w1 - __uint_as_float((uint32_t)h1 << 16));
          dH[(f * 64 + t) * 4 + jj] = (uint32_t)h0 | ((uint32_t)h1 << 16);
          dL[(f * 64 + t) * 4 + jj] = (uint32_t)l0 | ((uint32_t)l1 << 16);
        }
      }
    }
  }
}

// ---------------- K2s: per-node-row softmax stats (m, 1/S) ----------------
__global__ __launch_bounds__(256) void k2_stats() {
  const float* ws_q = g_ws + WS_Q;
  float* st = g_ws + WS_STATS;
  const int bi = blockIdx.x;          // b*N + i
  const int b  = bi >> 9;
  const int t  = threadIdx.x;
  __shared__ float red[4];
  __shared__ float red2[4];
  const float* qi = ws_q + bi * HH;
  const float q0 = qi[0], q1 = qi[1], q2 = qi[2], q3 = qi[3];
  const float q4 = qi[4], q5 = qi[5], q6 = qi[6], q7 = qi[7];
  const float* qb = ws_q + ((size_t)(b << 9)) * HH;
  const int j0 = t, j1 = t + 256;
  const float* qa = qb + j0 * HH;
  float s0 = (q0*qa[0]+q1*qa[1]+q2*qa[2]+q3*qa[3]+q4*qa[4]+q5*qa[5]+q6*qa[6]+q7*qa[7]) * INV_SQRT8;
  const float* qc = qb + j1 * HH;
  float s1 = (q0*qc[0]+q1*qc[1]+q2*qc[2]+q3*qc[3]+q4*qc[4]+q5*qc[5]+q6*qc[6]+q7*qc[7]) * INV_SQRT8;
  float m = fmaxf(s0, s1);
  for (int o = 32; o > 0; o >>= 1) m = fmaxf(m, __shfl_xor(m, o));
  if ((t & 63) == 0) red[t >> 6] = m;
  __syncthreads();
  m = fmaxf(fmaxf(red[0], red[1]), fmaxf(red[2], red[3]));
  float p0 = expf(s0 - m), p1 = expf(s1 - m);
  float s = p0 + p1;
  for (int o = 32; o > 0; o >>= 1) s += __shfl_xor(s, o);
  if ((t & 63) == 0) red2[t >> 6] = s;
  __syncthreads();
  if (t == 0) {
    st[bi * 2]     = m;
    st[bi * 2 + 1] = 1.0f / (red2[0] + red2[1] + red2[2] + red2[3]);
  }
}

// ---------------- K4: MFMA ef GEMM (bf16 edges) or r0 VALU fallback (f32 edges);
// single edges pass, in-kernel wn row+col, edge softmax + epilogue with
// full-line coalesced stores, aef per-col accum, awn fold. ----------------
__global__ __launch_bounds__(512, 4) void k4_main(
    const void* __restrict__ edges, float* __restrict__ out) {
  const float* nf  = g_ws + WS_NF;
  const float* qws = g_ws + WS_Q;
  const float* vws = g_ws + WS_V;
  const float* eWf = g_ws + WS_EW;
  const float* ebf = g_ws + WS_EB;
  const float* st  = g_ws + WS_STATS;
  const bool isf32 = g_ws[WS_FLAG + 0] != 0.0f;
  const int bi = blockIdx.x;          // b*N + i
  const int t  = threadIdx.x;         // 0..511
  const int lane = t & 63;
  const int wv = t >> 6;              // wave 0..7

  __shared__ uint4 bfrH_s[8][64];     // B frags (bf16 hi)   8 KB
  __shared__ uint4 bfrL_s[8][64];     // B frags (bf16 lo)   8 KB
  __shared__ float wn_s[NN];          // wn[i, j]
  __shared__ float wcol_s[NN];        // wn[j, i]
  __shared__ float se_s[NN];          // edge scores -> exp(p)
  __shared__ float nfi_s[FF];
  __shared__ float red[8];
  __shared__ float red2[8];
  __shared__ float aef_w[8][FF];
  __shared__ float awn_w[8][FF];

  // ---- stage B fragments (512 x uint4 each) ----
  ((uint4*)bfrH_s)[t] = ((const uint4*)(g_ws + WS_EWFH))[t];
  ((uint4*)bfrL_s)[t] = ((const uint4*)(g_ws + WS_EWFL))[t];
  if (t < FF) nfi_s[t] = nf[bi * FF + t];

  // ---- node scores from q (symmetric sn): wn row + column ----
  const float m_i   = st[bi * 2];
  const float inv_i = st[bi * 2 + 1];
  const float* qi = qws + bi * HH;
  const float q0 = qi[0], q1 = qi[1], q2 = qi[2], q3 = qi[3];
  const float q4 = qi[4], q5 = qi[5], q6 = qi[6], q7 = qi[7];
  const int bbase = (bi >> 9) << 9;
  const float* qt = qws + ((size_t)(bbase + t)) * HH;
  const float s_t = (q0*qt[0]+q1*qt[1]+q2*qt[2]+q3*qt[3]
                    +q4*qt[4]+q5*qt[5]+q6*qt[6]+q7*qt[7]) * INV_SQRT8;
  wn_s[t] = expf(s_t - m_i) * inv_i;                    // wn[i, t]
  const float2 stt = ((const float2*)st)[bbase + t];
  wcol_s[t] = expf(s_t - stt.x) * stt.y;                // wn[t, i]
  __syncthreads();                                      // B0

  float* oute = out + 65536 + (size_t)bi * NN * EEF;

  if (!isf32) {
    // ================= MFMA path (bf16 edges) =================
    // A[i][k]: lane holds i=lane&15, k=(lane>>4)*8+j.  C: col=lane&15, row=(lane>>4)*4+r.
    const uint16_t* eb16 = (const uint16_t*)edges + ((size_t)bi * NN + wv * 64) * EEF;
    float eb_n[4];
#pragma unroll
    for (int nt = 0; nt < 4; ++nt) eb_n[nt] = ebf[nt * 16 + (lane & 15)];
    floatx4 acc4[4][4];
#pragma unroll
    for (int mt = 0; mt < 4; ++mt)
#pragma unroll
      for (int nt = 0; nt < 4; ++nt)
        acc4[mt][nt] = (floatx4){eb_n[nt], eb_n[nt], eb_n[nt], eb_n[nt]};

#pragma unroll
    for (int mt = 0; mt < 4; ++mt) {
      const uint16_t* ap = eb16 + (size_t)(mt * 16 + (lane & 15)) * EEF + ((lane >> 4) << 3);
      const short8 a0 = *(const short8*)(ap);
      const short8 a1 = *(const short8*)(ap + 32);
#pragma unroll
      for (int nt = 0; nt < 4; ++nt) {
        floatx4 c = acc4[mt][nt];
        c = __builtin_amdgcn_mfma_f32_16x16x32_bf16(a0, *(const short8*)&bfrH_s[nt][lane],     c, 0, 0, 0);
        c = __builtin_amdgcn_mfma_f32_16x16x32_bf16(a1, *(const short8*)&bfrH_s[4 + nt][lane], c, 0, 0, 0);
        c = __builtin_amdgcn_mfma_f32_16x16x32_bf16(a0, *(const short8*)&bfrL_s[nt][lane],     c, 0, 0, 0);
        c = __builtin_amdgcn_mfma_f32_16x16x32_bf16(a1, *(const short8*)&bfrL_s[4 + nt][lane], c, 0, 0, 0);
        acc4[mt][nt] = c;
      }
    }

    // ---- se_row = ef_row . v  (reduce over 16-lane col groups) ----
    float v_v[4];
#pragma unroll
    for (int nt = 0; nt < 4; ++nt) v_v[nt] = vws[bi * FF + nt * 16 + (lane & 15)];
#pragma unroll
    for (int mt = 0; mt < 4; ++mt) {
#pragma unroll
      for (int r = 0; r < 4; ++r) {
        float part = acc4[mt][0][r] * v_v[0] + acc4[mt][1][r] * v_v[1]
                   + acc4[mt][2][r] * v_v[2] + acc4[mt][3][r] * v_v[3];
        part += __shfl_xor(part, 1);
        part += __shfl_xor(part, 2);
        part += __shfl_xor(part, 4);
        part += __shfl_xor(part, 8);
        if ((lane & 15) == 0)
          se_s[wv * 64 + mt * 16 + ((lane >> 4) << 2) + r] = part;
      }
    }
    __syncthreads();                                    // B1

    // ---- softmax over 512 rows ----
    const float sev = se_s[t];
    float m = sev;
    for (int o = 32; o > 0; o >>= 1) m = fmaxf(m, __shfl_xor(m, o));
    if (lane == 0) red[wv] = m;
    __syncthreads();                                    // B2
    m = red[0];
#pragma unroll
    for (int w = 1; w < 8; ++w) m = fmaxf(m, red[w]);
    const float p = expf(sev - m);
    float ssum = p;
    for (int o = 32; o > 0; o >>= 1) ssum += __shfl_xor(ssum, o);
    if (lane == 0) red2[wv] = ssum;
    se_s[t] = p;
    __syncthreads();                                    // B2b
    float tot = red2[0];
#pragma unroll
    for (int w = 1; w < 8; ++w) tot += red2[w];
    const float inv_tot = 1.0f / tot;

    // ---- epilogue: full-line coalesced stores + aef accumulation ----
    float nf_v[4];
#pragma unroll
    for (int nt = 0; nt < 4; ++nt) nf_v[nt] = nfi_s[nt * 16 + (lane & 15)];
    float aef_v[4] = {0.f, 0.f, 0.f, 0.f};
#pragma unroll
    for (int mt = 0; mt < 4; ++mt) {
#pragma unroll
      for (int r = 0; r < 4; ++r) {
        const int row = wv * 64 + mt * 16 + ((lane >> 4) << 2) + r;
        const float we = se_s[row] * inv_tot;
        const float onewe = 1.0f + we;
        const float wnr = wn_s[row];
#pragma unroll
        for (int nt = 0; nt < 4; ++nt) {
          const float c = acc4[mt][nt][r];
          oute[(size_t)row * EEF + nt * 16 + (lane & 15)] = elu(c * onewe + wnr * nf_v[nt]);
          aef_v[nt] = fmaf(we, c, aef_v[nt]);
        }
      }
    }
#pragma unroll
    for (int nt = 0; nt < 4; ++nt) {
      float g = aef_v[nt];
      g += __shfl_xor(g, 16);
      g += __shfl_xor(g, 32);
      if (lane < 16) aef_w[wv][nt * 16 + lane] = g;
    }
  } else {
    // ================= VALU fallback (f32 edges) — r0 structure =================
    const size_t row = ((size_t)bi * NN + t) * EEF;
    const float4* epf = (const float4*)((const float*)edges + row);
    float acc[EEF];
#pragma unroll
    for (int k = 0; k < EEF; ++k) acc[k] = ebf[k];
#pragma unroll 1
    for (int c = 0; c < 8; ++c) {
      float4 u = epf[2 * c], w2 = epf[2 * c + 1];
      const float a0 = u.x,  a1 = u.y,  a2 = u.z,  a3 = u.w;
      const float a4 = w2.x, a5 = w2.y, a6 = w2.z, a7 = w2.w;
      const float* w = eWf + c * 8 * FF;               // uniform -> s_load stream
#pragma unroll
      for (int k = 0; k < FF; ++k) {
        float s = acc[k];
        s = fmaf(a0, w[k],        s);
        s = fmaf(a1, w[FF + k],   s);
        s = fmaf(a2, w[2*FF + k], s);
        s = fmaf(a3, w[3*FF + k], s);
        s = fmaf(a4, w[4*FF + k], s);
        s = fmaf(a5, w[5*FF + k], s);
        s = fmaf(a6, w[6*FF + k], s);
        s = fmaf(a7, w[7*FF + k], s);
        acc[k] = s;
      }
    }
    const float* vi = vws + bi * FF;
    float se = 0.f;
#pragma unroll
    for (int k = 0; k < EEF; ++k) se += acc[k] * vi[k];
    se_s[t] = se;
    __syncthreads();                                    // B1
    float m = se;
    for (int o = 32; o > 0; o >>= 1) m = fmaxf(m, __shfl_xor(m, o));
    if (lane == 0) red[wv] = m;
    __syncthreads();                                    // B2
    m = red[0];
#pragma unroll
    for (int w = 1; w < 8; ++w) m = fmaxf(m, red[w]);
    const float p = expf(se - m);
    float ssum = p;
    for (int o = 32; o > 0; o >>= 1) ssum += __shfl_xor(ssum, o);
    if (lane == 0) red2[wv] = ssum;
    __syncthreads();                                    // B2b
    float tot = red2[0];
#pragma unroll
    for (int w = 1; w < 8; ++w) tot += red2[w];
    const float we = p / tot;

    const float wnj = wn_s[t];
    const float onewe = 1.0f + we;
    float4* orow = (float4*)(oute + (size_t)t * EEF);
#pragma unroll
    for (int c = 0; c < 16; ++c) {
      float4 o;
      o.x = elu(acc[4*c]   * onewe + wnj * nfi_s[4*c]);
      o.y = elu(acc[4*c+1] * onewe + wnj * nfi_s[4*c+1]);
      o.z = elu(acc[4*c+2] * onewe + wnj * nfi_s[4*c+2]);
      o.w = elu(acc[4*c+3] * onewe + wnj * nfi_s[4*c+3]);
      orow[c] = o;
      acc[4*c]   *= we;
      acc[4*c+1] *= we;
      acc[4*c+2] *= we;
      acc[4*c+3] *= we;
    }
#pragma unroll
    for (int k = 0; k < EEF; ++k) {
      float g = acc[k];
      g += __shfl_xor(g, 32);
      g += __shfl_xor(g, 16);
      g += __shfl_xor(g, 8);
      g += __shfl_xor(g, 4);
      g += __shfl_xor(g, 2);
      g += __shfl_xor(g, 1);
      acc[k] = g;
    }
    if (lane == 0) {
#pragma unroll
      for (int k = 0; k < EEF; ++k) aef_w[wv][k] = acc[k];
    }
  }

  // ---- awn[b,i,k] = sum_j wn[b,j,i]*nf[b,j,k]  (folded k3; nf is L2-hot) ----
  float awn_acc = 0.f;
  {
    const float* nfb = nf + (size_t)bbase * FF;
#pragma unroll 8
    for (int jj = 0; jj < 64; ++jj) {
      const int j = wv * 64 + jj;
      awn_acc = fmaf(wcol_s[j], nfb[(size_t)j * FF + lane], awn_acc);
    }
  }
  awn_w[wv][lane] = awn_acc;
  __syncthreads();                                      // B3

  // ---- node output (f32) ----
  if (t < FF) {
    float sum = nfi_s[t];
#pragma unroll
    for (int w = 0; w < 8; ++w) sum += aef_w[w][t] + awn_w[w][t];
    out[bi * FF + t] = elu(sum);
  }
}

extern "C" void kernel_launch(void* const* d_in, const int* in_sizes, int n_in,
                              void* d_out, int out_size, void* d_ws, size_t ws_size,
                              hipStream_t stream) {
  // Identify inputs by element count (robust to mask-dropping / reordering).
  const void* nodes = nullptr; const void* edges = nullptr;
  const void* node_W = nullptr; const void* node_b = nullptr;
  const void* edge_W = nullptr; const void* edge_b = nullptr;
  const void* att_W = nullptr;
  int bias_seen = 0;
  for (int i = 0; i < n_in; ++i) {
    switch (in_sizes[i]) {
      case 33554432: edges  = d_in[i]; break;
      case 131072:   nodes  = d_in[i]; break;
      case 8192:     node_W = d_in[i]; break;
      case 4096:     edge_W = d_in[i]; break;
      case 512:      att_W  = d_in[i]; break;
      case 64:       if (bias_seen++ == 0) node_b = d_in[i]; else edge_b = d_in[i]; break;
      default: break;  // mask or scalars: unused
    }
  }
  float* out = (float*)d_out;

  k0_detect<<<dim3(7), dim3(256), 0, stream>>>(
      (const uint16_t*)edges, 33554432, (const uint16_t*)nodes, 131072,
      (const uint16_t*)node_W, 8192, (const uint16_t*)node_b, 64,
      (const uint16_t*)edge_W, 4096, (const uint16_t*)edge_b, 64,
      (const uint16_t*)att_W, 512);
  k1_nf_q_v<<<dim3(BB * NN), dim3(64), 0, stream>>>(nodes, node_W, node_b,
                                                    att_W, edge_W, edge_b);
  k2_stats<<<dim3(BB * NN), dim3(256), 0, stream>>>();
  k4_main<<<dim3(BB * NN), dim3(512), 0, stream>>>(edges, out);
}

// Round 5
// 444.096 us; speedup vs baseline: 1.5446x; 1.5446x over previous
//
#include <hip/hip_runtime.h>
#include <stdint.h>

#define BB 2
#define NN 512
#define ENF 128
#define EEF 64
#define FF 64
#define HH 8

// static scratch offsets (floats)
#define WS_NF    0        // [B*N*64]   = 65536
#define WS_Q     65536    // [B*N*8]    = 8192
#define WS_V     73728    // [B*N*64]   = 65536  (v = att_W@q * 1/sqrt(8); f32 path)
#define WS_EW    139264   // [64*64]    = 4096   (f32 weights, fallback path)
#define WS_EB    143360   // [64]
#define WS_M     143424   // [64*8]     = 512    (M = edge_W @ att_W)
#define WS_STATS 143936   // [B*N*2]    = 2048   (m, 1/S per node row)
#define WS_FLAG  145984   // [7] flags + 1 pad
#define WS_EWFH  145992   // [8 frag][64 lane][4 u32] bf16-hi B fragments = 4096
#define WS_EWFL  150088   // same, bf16-lo residual                      = 4096
#define WS_TOTAL 154184
// flag index: 0=edges 1=nodes 2=node_W 3=node_b 4=edge_W 5=edge_b 6=att_W

__device__ __align__(16) float g_ws[WS_TOTAL];

using short8  = __attribute__((ext_vector_type(8))) short;
using floatx4 = __attribute__((ext_vector_type(4))) float;

__device__ __forceinline__ float bf2f(uint16_t u) {
  return __uint_as_float(((uint32_t)u) << 16);
}
__device__ __forceinline__ uint16_t f2bf(float f) {   // RNE f32->bf16
  uint32_t u = __float_as_uint(f);
  return (uint16_t)((u + 0x7FFFu + ((u >> 16) & 1u)) >> 16);
}
__device__ __forceinline__ float load1(const void* p, size_t i, bool isf32) {
  return isf32 ? ((const float*)p)[i] : bf2f(((const uint16_t*)p)[i]);
}
__device__ __forceinline__ float elu(float x) {
  return x > 0.f ? x : expf(x) - 1.0f;
}

constexpr float INV_SQRT8 = 0.35355339059327373f;

// ------------- K0: per-array dtype detection (f32 vs bf16 in memory) -------------
__global__ __launch_bounds__(256) void k0_detect(
    const uint16_t* p0, int c0, const uint16_t* p1, int c1,
    const uint16_t* p2, int c2, const uint16_t* p3, int c3,
    const uint16_t* p4, int c4, const uint16_t* p5, int c5,
    const uint16_t* p6, int c6) {
  const uint16_t* ptrs[7] = {p0, p1, p2, p3, p4, p5, p6};
  const int cnts[7] = {c0, c1, c2, c3, c4, c5, c6};
  const int a = blockIdx.x;
  const uint16_t* e = ptrs[a];
  int S = cnts[a] / 2; if (S > 2048) S = 2048;
  const int t = threadIdx.x;
  int hi = 0, z0 = 0, nz1 = 0;
  for (int i = t; i < S; i += 256) {
    uint16_t h0 = e[2 * i], h1 = e[2 * i + 1];
    if (((h0 >> 7) & 0xFF) >= 0x90) hi++;
    if (h0 == 0) z0++;
    if (h1 != 0) nz1++;
  }
  for (int o = 32; o > 0; o >>= 1) {
    hi += __shfl_xor(hi, o); z0 += __shfl_xor(z0, o); nz1 += __shfl_xor(nz1, o);
  }
  __shared__ int r[3][4];
  if ((t & 63) == 0) { int w = t >> 6; r[0][w] = hi; r[1][w] = z0; r[2][w] = nz1; }
  __syncthreads();
  if (t == 0) {
    int H  = r[0][0] + r[0][1] + r[0][2] + r[0][3];
    int Z  = r[1][0] + r[1][1] + r[1][2] + r[1][3];
    int NZ = r[2][0] + r[2][1] + r[2][2] + r[2][3];
    g_ws[WS_FLAG + a] =
        (H > S / 16 || (Z * 8 > S * 3 && NZ * 8 > S * 3)) ? 1.0f : 0.0f;
  }
}

// ---- K1: nf, q, v (+ upcast edge_W/edge_b, M = edge_W@att_W, pack MFMA B frags) ----
// 4 waves/block, one node per wave (was 1 wave/block: latency-bound).
__global__ __launch_bounds__(256) void k1_nf_q_v(
    const void* __restrict__ nodes, const void* __restrict__ node_W,
    const void* __restrict__ node_b, const void* __restrict__ att_W,
    const void* __restrict__ edge_W, const void* __restrict__ edge_b) {
  float* nf  = g_ws + WS_NF;
  float* q   = g_ws + WS_Q;
  float* v   = g_ws + WS_V;
  float* eWf = g_ws + WS_EW;
  float* ebf = g_ws + WS_EB;
  float* Mf  = g_ws + WS_M;
  const float* fl = g_ws + WS_FLAG;
  const bool fNodes = fl[1] != 0.f, fNW = fl[2] != 0.f, fNB = fl[3] != 0.f;
  const bool fEW = fl[4] != 0.f, fEB = fl[5] != 0.f, fAW = fl[6] != 0.f;
  const int t    = threadIdx.x;
  const int lane = t & 63;
  const int wv   = t >> 6;
  const int bi   = blockIdx.x * 4 + wv;      // b*N + n
  __shared__ float nd[4][ENF];
  __shared__ float nf_s[4][FF];
  __shared__ float q_s[4][HH];
  nd[wv][lane]      = load1(nodes, (size_t)bi * ENF + lane, fNodes);
  nd[wv][lane + 64] = load1(nodes, (size_t)bi * ENF + lane + 64, fNodes);
  __syncthreads();
  float acc = load1(node_b, lane, fNB);
#pragma unroll 8
  for (int e = 0; e < ENF; ++e) acc += nd[wv][e] * load1(node_W, e * FF + lane, fNW);
  nf[bi * FF + lane] = acc;
  nf_s[wv][lane] = acc;
  __syncthreads();
  if (lane < HH) {
    float s = 0.f;
#pragma unroll
    for (int k = 0; k < FF; ++k) s += nf_s[wv][k] * load1(att_W, k * HH + lane, fAW);
    q[bi * HH + lane] = s;
    q_s[wv][lane] = s;
  }
  __syncthreads();
  {
    float s = 0.f;
#pragma unroll
    for (int h = 0; h < HH; ++h) s += load1(att_W, lane * HH + h, fAW) * q_s[wv][h];
    v[bi * FF + lane] = s * INV_SQRT8;       // fold 1/sqrt(D_EDGE)
  }
  if (bi == 0) {                             // wave 0 of block 0 only; no barriers inside
    for (int idx = lane; idx < EEF * FF; idx += 64)
      eWf[idx] = load1(edge_W, idx, fEW);
    ebf[lane] = load1(edge_b, lane, fEB);
    // M[c][h] = sum_k edge_W[c,k] * att_W[k,h]   (lane owns row c = lane)
    float mrow[HH];
#pragma unroll
    for (int h = 0; h < HH; ++h) mrow[h] = 0.f;
    for (int k = 0; k < FF; ++k) {
      float w = load1(edge_W, (size_t)lane * FF + k, fEW);
#pragma unroll
      for (int h = 0; h < HH; ++h) mrow[h] += w * load1(att_W, k * HH + h, fAW);
    }
#pragma unroll
    for (int h = 0; h < HH; ++h) Mf[lane * HH + h] = mrow[h];
    // pack B fragments for mfma_f32_16x16x32_bf16, split-precision (r4-validated)
    uint32_t* dH = (uint32_t*)(g_ws + WS_EWFH);
    uint32_t* dL = (uint32_t*)(g_ws + WS_EWFL);
#pragma unroll
    for (int ks = 0; ks < 2; ++ks) {
#pragma unroll
      for (int nt = 0; nt < 4; ++nt) {
        const int f = ks * 4 + nt;
        const int n = nt * 16 + (lane & 15);
        const int e0 = ks * 32 + ((lane >> 4) << 3);
#pragma unroll
        for (int jj = 0; jj < 4; ++jj) {
          float w0 = load1(edge_W, (size_t)(e0 + 2 * jj) * FF + n, fEW);
          float w1 = load1(edge_W, (size_t)(e0 + 2 * jj + 1) * FF + n, fEW);
          uint16_t h0 = f2bf(w0);
          uint16_t h1 = f2bf(w1);
          uint16_t l0 = f2bf(w0 - __uint_as_float((uint32_t)h0 << 16));
          uint16_t l1 = f2bf(w1 - __uint_as_float((uint32_t)h1 << 16));
          dH[(f * 64 + lane) * 4 + jj] = (uint32_t)h0 | ((uint32_t)h1 << 16);
          dL[(f * 64 + lane) * 4 + jj] = (uint32_t)l0 | ((uint32_t)l1 << 16);
        }
      }
    }
  }
}

// ---------------- K2s: per-node-row softmax stats (m, 1/S) ----------------
__global__ __launch_bounds__(256) void k2_stats() {
  const float* ws_q = g_ws + WS_Q;
  float* st = g_ws + WS_STATS;
  const int bi = blockIdx.x;          // b*N + i
  const int b  = bi >> 9;
  const int t  = threadIdx.x;
  __shared__ float red[4];
  __shared__ float red2[4];
  const float* qi = ws_q + bi * HH;
  const float q0 = qi[0], q1 = qi[1], q2 = qi[2], q3 = qi[3];
  const float q4 = qi[4], q5 = qi[5], q6 = qi[6], q7 = qi[7];
  const float* qb = ws_q + ((size_t)(b << 9)) * HH;
  const int j0 = t, j1 = t + 256;
  const float* qa = qb + j0 * HH;
  float s0 = (q0*qa[0]+q1*qa[1]+q2*qa[2]+q3*qa[3]+q4*qa[4]+q5*qa[5]+q6*qa[6]+q7*qa[7]) * INV_SQRT8;
  const float* qc = qb + j1 * HH;
  float s1 = (q0*qc[0]+q1*qc[1]+q2*qc[2]+q3*qc[3]+q4*qc[4]+q5*qc[5]+q6*qc[6]+q7*qc[7]) * INV_SQRT8;
  float m = fmaxf(s0, s1);
  for (int o = 32; o > 0; o >>= 1) m = fmaxf(m, __shfl_xor(m, o));
  if ((t & 63) == 0) red[t >> 6] = m;
  __syncthreads();
  m = fmaxf(fmaxf(red[0], red[1]), fmaxf(red[2], red[3]));
  float p0 = expf(s0 - m), p1 = expf(s1 - m);
  float s = p0 + p1;
  for (int o = 32; o > 0; o >>= 1) s += __shfl_xor(s, o);
  if ((t & 63) == 0) red2[t >> 6] = s;
  __syncthreads();
  if (t == 0) {
    st[bi * 2]     = m;
    st[bi * 2 + 1] = 1.0f / (red2[0] + red2[1] + red2[2] + red2[3]);
  }
}

// ---------------- K4 (bf16 edges): score-first (se = e.u), softmax, then
// tile-by-tile MFMA GEMM + fused epilogue. Only 16 accumulators live at a
// time -> no spills; B fragments loop-invariant in VGPRs. ----------------
__global__ __launch_bounds__(512, 4) void k4_bf16(
    const void* __restrict__ edges, float* __restrict__ out) {
  if (g_ws[WS_FLAG + 0] != 0.0f) return;     // edges are f32 -> k4_f32 handles
  const float* nf  = g_ws + WS_NF;
  const float* qws = g_ws + WS_Q;
  const float* ebf = g_ws + WS_EB;
  const float* Mf  = g_ws + WS_M;
  const float* st  = g_ws + WS_STATS;
  const int bi = blockIdx.x;          // b*N + i
  const int t  = threadIdx.x;         // 0..511
  const int lane = t & 63;
  const int wv = t >> 6;              // wave 0..7, owns rows wv*64..wv*64+63

  __shared__ float wn_s[NN];
  __shared__ float wcol_s[NN];
  __shared__ float se_s[NN];
  __shared__ float u_s[EEF];
  __shared__ float nfi_s[FF];
  __shared__ float red[8], red2[8];
  __shared__ float aef_w[8][FF];
  __shared__ float awn_w[8][FF];

  if (t < FF) nfi_s[t] = nf[bi * FF + t];
  if (t < EEF) {
    const float* qi = qws + bi * HH;  // uniform -> s_load
    const float* mr = Mf + t * HH;
    float s = 0.f;
#pragma unroll
    for (int h = 0; h < HH; ++h) s += mr[h] * qi[h];
    u_s[t] = s * INV_SQRT8;           // u = (edge_W @ att_W @ q_i)/sqrt(8)
  }
  // node scores from q (symmetric sn): wn row + column
  const float m_i   = st[bi * 2];
  const float inv_i = st[bi * 2 + 1];
  const float* qi = qws + bi * HH;
  const float q0 = qi[0], q1 = qi[1], q2 = qi[2], q3 = qi[3];
  const float q4 = qi[4], q5 = qi[5], q6 = qi[6], q7 = qi[7];
  const int bbase = (bi >> 9) << 9;
  const float* qt = qws + ((size_t)(bbase + t)) * HH;
  const float s_t = (q0*qt[0]+q1*qt[1]+q2*qt[2]+q3*qt[3]
                    +q4*qt[4]+q5*qt[5]+q6*qt[6]+q7*qt[7]) * INV_SQRT8;
  wn_s[t] = expf(s_t - m_i) * inv_i;                    // wn[i, t]
  const float2 stt = ((const float2*)st)[bbase + t];
  wcol_s[t] = expf(s_t - stt.x) * stt.y;                // wn[t, i]
  __syncthreads();                                      // B0

  // ---- pass A: se_j = e_row_j . u  (8 lanes per row, 1KB-contiguous loads) ----
  {
    float u8[8];
#pragma unroll
    for (int c = 0; c < 8; ++c) u8[c] = u_s[8 * (lane & 7) + c];
    const uint4* ep = (const uint4*)((const uint16_t*)edges
                      + ((size_t)bi * NN + wv * 64) * EEF);
#pragma unroll
    for (int it = 0; it < 8; ++it) {
      const int r = it * 8 + (lane >> 3);
      uint4 x = ep[(size_t)r * 8 + (lane & 7)];
      float p = __uint_as_float(x.x << 16)          * u8[0]
              + __uint_as_float(x.x & 0xFFFF0000u)  * u8[1]
              + __uint_as_float(x.y << 16)          * u8[2]
              + __uint_as_float(x.y & 0xFFFF0000u)  * u8[3]
              + __uint_as_float(x.z << 16)          * u8[4]
              + __uint_as_float(x.z & 0xFFFF0000u)  * u8[5]
              + __uint_as_float(x.w << 16)          * u8[6]
              + __uint_as_float(x.w & 0xFFFF0000u)  * u8[7];
      p += __shfl_xor(p, 1); p += __shfl_xor(p, 2); p += __shfl_xor(p, 4);
      if ((lane & 7) == 0) se_s[wv * 64 + r] = p;
    }
  }
  __syncthreads();                                      // B1

  // ---- softmax over 512 rows ----
  const float sev = se_s[t];
  float m = sev;
  for (int o = 32; o > 0; o >>= 1) m = fmaxf(m, __shfl_xor(m, o));
  if (lane == 0) red[wv] = m;
  __syncthreads();                                      // B2
  m = red[0];
#pragma unroll
  for (int w = 1; w < 8; ++w) m = fmaxf(m, red[w]);
  const float p = expf(sev - m);
  float ssum = p;
  for (int o = 32; o > 0; o >>= 1) ssum += __shfl_xor(ssum, o);
  if (lane == 0) red2[wv] = ssum;
  se_s[t] = p;
  __syncthreads();                                      // B2b
  float tot = red2[0];
#pragma unroll
  for (int w = 1; w < 8; ++w) tot += red2[w];
  const float inv_tot = 1.0f / tot;

  // ---- pass B: tiled MFMA GEMM + fused epilogue (16 rows per tile) ----
  // A[i][k]: lane holds i=lane&15, k=(lane>>4)*8+j. C: col=lane&15, row=(lane>>4)*4+r.
  short8 bh[8], bl[8];                                  // loop-invariant B frags
#pragma unroll
  for (int f = 0; f < 8; ++f) {
    uint4 h = ((const uint4*)(g_ws + WS_EWFH))[f * 64 + lane];
    uint4 l = ((const uint4*)(g_ws + WS_EWFL))[f * 64 + lane];
    bh[f] = *(const short8*)&h;
    bl[f] = *(const short8*)&l;
  }
  float eb_n[4], nf_v[4];
#pragma unroll
  for (int nt = 0; nt < 4; ++nt) {
    eb_n[nt] = ebf[nt * 16 + (lane & 15)];
    nf_v[nt] = nfi_s[nt * 16 + (lane & 15)];
  }
  float aef_v[4] = {0.f, 0.f, 0.f, 0.f};
  const uint16_t* eb16 = (const uint16_t*)edges + ((size_t)bi * NN + wv * 64) * EEF;
  float* oute = out + 65536 + ((size_t)bi * NN + wv * 64) * EEF;
#pragma unroll 1
  for (int mt = 0; mt < 4; ++mt) {
    const uint16_t* ap = eb16 + (size_t)(mt * 16 + (lane & 15)) * EEF + ((lane >> 4) << 3);
    const short8 a0 = *(const short8*)(ap);
    const short8 a1 = *(const short8*)(ap + 32);
    floatx4 acc[4];
#pragma unroll
    for (int nt = 0; nt < 4; ++nt)
      acc[nt] = (floatx4){eb_n[nt], eb_n[nt], eb_n[nt], eb_n[nt]};
#pragma unroll
    for (int nt = 0; nt < 4; ++nt) {
      floatx4 c = acc[nt];
      c = __builtin_amdgcn_mfma_f32_16x16x32_bf16(a0, bh[nt],     c, 0, 0, 0);
      c = __builtin_amdgcn_mfma_f32_16x16x32_bf16(a1, bh[4 + nt], c, 0, 0, 0);
      c = __builtin_amdgcn_mfma_f32_16x16x32_bf16(a0, bl[nt],     c, 0, 0, 0);
      c = __builtin_amdgcn_mfma_f32_16x16x32_bf16(a1, bl[4 + nt], c, 0, 0, 0);
      acc[nt] = c;
    }
#pragma unroll
    for (int r = 0; r < 4; ++r) {
      const int row = mt * 16 + ((lane >> 4) << 2) + r;
      const float we = se_s[wv * 64 + row] * inv_tot;
      const float wnr = wn_s[wv * 64 + row];
      const float onewe = 1.0f + we;
#pragma unroll
      for (int nt = 0; nt < 4; ++nt) {
        const float c = acc[nt][r];
        oute[(size_t)row * EEF + nt * 16 + (lane & 15)] = elu(c * onewe + wnr * nf_v[nt]);
        aef_v[nt] = fmaf(we, c, aef_v[nt]);
      }
    }
  }
#pragma unroll
  for (int nt = 0; nt < 4; ++nt) {
    float g = aef_v[nt];
    g += __shfl_xor(g, 16);
    g += __shfl_xor(g, 32);
    if (lane < 16) aef_w[wv][nt * 16 + lane] = g;
  }

  // ---- awn[b,i,k] = sum_j wn[b,j,i]*nf[b,j,k]  (folded k3; nf is L2-hot) ----
  float awn_acc = 0.f;
  {
    const float* nfb = nf + (size_t)bbase * FF;
#pragma unroll 8
    for (int jj = 0; jj < 64; ++jj) {
      const int j = wv * 64 + jj;
      awn_acc = fmaf(wcol_s[j], nfb[(size_t)j * FF + lane], awn_acc);
    }
  }
  awn_w[wv][lane] = awn_acc;
  __syncthreads();                                      // B3

  if (t < FF) {
    float sum = nfi_s[t];
#pragma unroll
    for (int w = 0; w < 8; ++w) sum += aef_w[w][t] + awn_w[w][t];
    out[bi * FF + t] = elu(sum);
  }
}

// ---------------- K4 (f32 edges): VALU fallback, own kernel so its register
// pressure can't contaminate the bf16 kernel's allocation. ----------------
__global__ __launch_bounds__(512) void k4_f32(
    const void* __restrict__ edges, float* __restrict__ out) {
  if (g_ws[WS_FLAG + 0] == 0.0f) return;     // edges are bf16 -> k4_bf16 handles
  const float* nf  = g_ws + WS_NF;
  const float* qws = g_ws + WS_Q;
  const float* vws = g_ws + WS_V;
  const float* eWf = g_ws + WS_EW;
  const float* ebf = g_ws + WS_EB;
  const float* st  = g_ws + WS_STATS;
  const int bi = blockIdx.x;
  const int t  = threadIdx.x;
  const int lane = t & 63;
  const int wv = t >> 6;

  __shared__ float wn_s[NN];
  __shared__ float wcol_s[NN];
  __shared__ float nfi_s[FF];
  __shared__ float red[8], red2[8];
  __shared__ float aef_w[8][FF];
  __shared__ float awn_w[8][FF];

  if (t < FF) nfi_s[t] = nf[bi * FF + t];
  const float m_i   = st[bi * 2];
  const float inv_i = st[bi * 2 + 1];
  const float* qi = qws + bi * HH;
  const float q0 = qi[0], q1 = qi[1], q2 = qi[2], q3 = qi[3];
  const float q4 = qi[4], q5 = qi[5], q6 = qi[6], q7 = qi[7];
  const int bbase = (bi >> 9) << 9;
  const float* qt = qws + ((size_t)(bbase + t)) * HH;
  const float s_t = (q0*qt[0]+q1*qt[1]+q2*qt[2]+q3*qt[3]
                    +q4*qt[4]+q5*qt[5]+q6*qt[6]+q7*qt[7]) * INV_SQRT8;
  wn_s[t] = expf(s_t - m_i) * inv_i;
  const float2 stt = ((const float2*)st)[bbase + t];
  wcol_s[t] = expf(s_t - stt.x) * stt.y;
  __syncthreads();

  const size_t row = ((size_t)bi * NN + t) * EEF;
  const float4* epf = (const float4*)((const float*)edges + row);
  float acc[EEF];
#pragma unroll
  for (int k = 0; k < EEF; ++k) acc[k] = ebf[k];
#pragma unroll 1
  for (int c = 0; c < 8; ++c) {
    float4 u = epf[2 * c], w2 = epf[2 * c + 1];
    const float a0 = u.x,  a1 = u.y,  a2 = u.z,  a3 = u.w;
    const float a4 = w2.x, a5 = w2.y, a6 = w2.z, a7 = w2.w;
    const float* w = eWf + c * 8 * FF;               // uniform -> s_load stream
#pragma unroll
    for (int k = 0; k < FF; ++k) {
      float s = acc[k];
      s = fmaf(a0, w[k],        s);
      s = fmaf(a1, w[FF + k],   s);
      s = fmaf(a2, w[2*FF + k], s);
      s = fmaf(a3, w[3*FF + k], s);
      s = fmaf(a4, w[4*FF + k], s);
      s = fmaf(a5, w[5*FF + k], s);
      s = fmaf(a6, w[6*FF + k], s);
      s = fmaf(a7, w[7*FF + k], s);
      acc[k] = s;
    }
  }
  const float* vi = vws + bi * FF;
  float se = 0.f;
#pragma unroll
  for (int k = 0; k < EEF; ++k) se += acc[k] * vi[k];

  float m = se;
  for (int o = 32; o > 0; o >>= 1) m = fmaxf(m, __shfl_xor(m, o));
  if (lane == 0) red[wv] = m;
  __syncthreads();
  m = red[0];
#pragma unroll
  for (int w = 1; w < 8; ++w) m = fmaxf(m, red[w]);
  const float p = expf(se - m);
  float ssum = p;
  for (int o = 32; o > 0; o >>= 1) ssum += __shfl_xor(ssum, o);
  if (lane == 0) red2[wv] = ssum;
  __syncthreads();
  float tot = red2[0];
#pragma unroll
  for (int w = 1; w < 8; ++w) tot += red2[w];
  const float we = p / tot;

  const float wnj = wn_s[t];
  const float onewe = 1.0f + we;
  float4* orow = (float4*)(out + 65536 + ((size_t)bi * NN + t) * EEF);
#pragma unroll
  for (int c = 0; c < 16; ++c) {
    float4 o;
    o.x = elu(acc[4*c]   * onewe + wnj * nfi_s[4*c]);
    o.y = elu(acc[4*c+1] * onewe + wnj * nfi_s[4*c+1]);
    o.z = elu(acc[4*c+2] * onewe + wnj * nfi_s[4*c+2]);
    o.w = elu(acc[4*c+3] * onewe + wnj * nfi_s[4*c+3]);
    orow[c] = o;
    acc[4*c]   *= we;
    acc[4*c+1] *= we;
    acc[4*c+2] *= we;
    acc[4*c+3] *= we;
  }
#pragma unroll
  for (int k = 0; k < EEF; ++k) {
    float g = acc[k];
    g += __shfl_xor(g, 32);
    g += __shfl_xor(g, 16);
    g += __shfl_xor(g, 8);
    g += __shfl_xor(g, 4);
    g += __shfl_xor(g, 2);
    g += __shfl_xor(g, 1);
    acc[k] = g;
  }
  if (lane == 0) {
#pragma unroll
    for (int k = 0; k < EEF; ++k) aef_w[wv][k] = acc[k];
  }

  float awn_acc = 0.f;
  {
    const float* nfb = nf + (size_t)bbase * FF;
#pragma unroll 8
    for (int jj = 0; jj < 64; ++jj) {
      const int j = wv * 64 + jj;
      awn_acc = fmaf(wcol_s[j], nfb[(size_t)j * FF + lane], awn_acc);
    }
  }
  awn_w[wv][lane] = awn_acc;
  __syncthreads();

  if (t < FF) {
    float sum = nfi_s[t];
#pragma unroll
    for (int w = 0; w < 8; ++w) sum += aef_w[w][t] + awn_w[w][t];
    out[bi * FF + t] = elu(sum);
  }
}

extern "C" void kernel_launch(void* const* d_in, const int* in_sizes, int n_in,
                              void* d_out, int out_size, void* d_ws, size_t ws_size,
                              hipStream_t stream) {
  // Identify inputs by element count (robust to mask-dropping / reordering).
  const void* nodes = nullptr; const void* edges = nullptr;
  const void* node_W = nullptr; const void* node_b = nullptr;
  const void* edge_W = nullptr; const void* edge_b = nullptr;
  const void* att_W = nullptr;
  int bias_seen = 0;
  for (int i = 0; i < n_in; ++i) {
    switch (in_sizes[i]) {
      case 33554432: edges  = d_in[i]; break;
      case 131072:   nodes  = d_in[i]; break;
      case 8192:     node_W = d_in[i]; break;
      case 4096:     edge_W = d_in[i]; break;
      case 512:      att_W  = d_in[i]; break;
      case 64:       if (bias_seen++ == 0) node_b = d_in[i]; else edge_b = d_in[i]; break;
      default: break;  // mask or scalars: unused
    }
  }
  float* out = (float*)d_out;

  k0_detect<<<dim3(7), dim3(256), 0, stream>>>(
      (const uint16_t*)edges, 33554432, (const uint16_t*)nodes, 131072,
      (const uint16_t*)node_W, 8192, (const uint16_t*)node_b, 64,
      (const uint16_t*)edge_W, 4096, (const uint16_t*)edge_b, 64,
      (const uint16_t*)att_W, 512);
  k1_nf_q_v<<<dim3(BB * NN / 4), dim3(256), 0, stream>>>(nodes, node_W, node_b,
                                                         att_W, edge_W, edge_b);
  k2_stats<<<dim3(BB * NN), dim3(256), 0, stream>>>();
  k4_bf16<<<dim3(BB * NN), dim3(512), 0, stream>>>(edges, out);
  k4_f32<<<dim3(BB * NN), dim3(512), 0, stream>>>(edges, out);
}

// Round 6
// 368.578 us; speedup vs baseline: 1.8611x; 1.2049x over previous
//
#include <hip/hip_runtime.h>
#include <stdint.h>

#define BB 2
#define NN 512
#define ENF 128
#define EEF 64
#define FF 64
#define HH 8

// static scratch offsets (floats)
#define WS_NF    0        // [B*N*64]   = 65536
#define WS_Q     65536    // [B*N*8]    = 8192
#define WS_V     73728    // [B*N*64]   = 65536  (v = att_W@q * 1/sqrt(8); legacy)
#define WS_EW    139264   // [64*64]    = 4096   (f32 weights)
#define WS_EB    143360   // [64]
#define WS_M     143424   // [64*8]     = 512    (M = edge_W @ att_W)
#define WS_STATS 143936   // [B*N*2]    = 2048   (m, 1/S per node row)
#define WS_FLAG  145984   // [7] flags + 1 pad
#define WS_EWFH  145992   // [8 frag][64 lane][4 u32] bf16-hi B fragments = 4096
#define WS_EWFL  150088   // same, bf16-lo residual                      = 4096
#define WS_TOTAL 154184
// flag index: 0=edges 1=nodes 2=node_W 3=node_b 4=edge_W 5=edge_b 6=att_W

__device__ __align__(16) float g_ws[WS_TOTAL];

using short8  = __attribute__((ext_vector_type(8))) short;
using floatx4 = __attribute__((ext_vector_type(4))) float;

__device__ __forceinline__ float bf2f(uint16_t u) {
  return __uint_as_float(((uint32_t)u) << 16);
}
__device__ __forceinline__ uint16_t f2bf(float f) {   // RNE f32->bf16
  uint32_t u = __float_as_uint(f);
  return (uint16_t)((u + 0x7FFFu + ((u >> 16) & 1u)) >> 16);
}
// split two f32 into packed bf16 hi pair + bf16 residual-lo pair
__device__ __forceinline__ void split2(float f0, float f1, uint32_t& hi, uint32_t& lo) {
  uint16_t h0 = f2bf(f0), h1 = f2bf(f1);
  float r0 = f0 - bf2f(h0), r1 = f1 - bf2f(h1);
  uint16_t l0 = f2bf(r0), l1 = f2bf(r1);
  hi = (uint32_t)h0 | ((uint32_t)h1 << 16);
  lo = (uint32_t)l0 | ((uint32_t)l1 << 16);
}
__device__ __forceinline__ float load1(const void* p, size_t i, bool isf32) {
  return isf32 ? ((const float*)p)[i] : bf2f(((const uint16_t*)p)[i]);
}
__device__ __forceinline__ float elu(float x) {
  return x > 0.f ? x : expf(x) - 1.0f;
}

constexpr float INV_SQRT8 = 0.35355339059327373f;

// ------------- K0: per-array dtype detection (f32 vs bf16 in memory) -------------
__global__ __launch_bounds__(256) void k0_detect(
    const uint16_t* p0, int c0, const uint16_t* p1, int c1,
    const uint16_t* p2, int c2, const uint16_t* p3, int c3,
    const uint16_t* p4, int c4, const uint16_t* p5, int c5,
    const uint16_t* p6, int c6) {
  const uint16_t* ptrs[7] = {p0, p1, p2, p3, p4, p5, p6};
  const int cnts[7] = {c0, c1, c2, c3, c4, c5, c6};
  const int a = blockIdx.x;
  const uint16_t* e = ptrs[a];
  int S = cnts[a] / 2; if (S > 2048) S = 2048;
  const int t = threadIdx.x;
  int hi = 0, z0 = 0, nz1 = 0;
  for (int i = t; i < S; i += 256) {
    uint16_t h0 = e[2 * i], h1 = e[2 * i + 1];
    if (((h0 >> 7) & 0xFF) >= 0x90) hi++;
    if (h0 == 0) z0++;
    if (h1 != 0) nz1++;
  }
  for (int o = 32; o > 0; o >>= 1) {
    hi += __shfl_xor(hi, o); z0 += __shfl_xor(z0, o); nz1 += __shfl_xor(nz1, o);
  }
  __shared__ int r[3][4];
  if ((t & 63) == 0) { int w = t >> 6; r[0][w] = hi; r[1][w] = z0; r[2][w] = nz1; }
  __syncthreads();
  if (t == 0) {
    int H  = r[0][0] + r[0][1] + r[0][2] + r[0][3];
    int Z  = r[1][0] + r[1][1] + r[1][2] + r[1][3];
    int NZ = r[2][0] + r[2][1] + r[2][2] + r[2][3];
    g_ws[WS_FLAG + a] =
        (H > S / 16 || (Z * 8 > S * 3 && NZ * 8 > S * 3)) ? 1.0f : 0.0f;
  }
}

// ---- K1: nf, q, v (+ upcast edge_W/edge_b, M = edge_W@att_W, pack MFMA B frags) ----
__global__ __launch_bounds__(256) void k1_nf_q_v(
    const void* __restrict__ nodes, const void* __restrict__ node_W,
    const void* __restrict__ node_b, const void* __restrict__ att_W,
    const void* __restrict__ edge_W, const void* __restrict__ edge_b) {
  float* nf  = g_ws + WS_NF;
  float* q   = g_ws + WS_Q;
  float* v   = g_ws + WS_V;
  float* eWf = g_ws + WS_EW;
  float* ebf = g_ws + WS_EB;
  float* Mf  = g_ws + WS_M;
  const float* fl = g_ws + WS_FLAG;
  const bool fNodes = fl[1] != 0.f, fNW = fl[2] != 0.f, fNB = fl[3] != 0.f;
  const bool fEW = fl[4] != 0.f, fEB = fl[5] != 0.f, fAW = fl[6] != 0.f;
  const int t    = threadIdx.x;
  const int lane = t & 63;
  const int wv   = t >> 6;
  const int bi   = blockIdx.x * 4 + wv;      // b*N + n
  __shared__ float nd[4][ENF];
  __shared__ float nf_s[4][FF];
  __shared__ float q_s[4][HH];
  nd[wv][lane]      = load1(nodes, (size_t)bi * ENF + lane, fNodes);
  nd[wv][lane + 64] = load1(nodes, (size_t)bi * ENF + lane + 64, fNodes);
  __syncthreads();
  float acc = load1(node_b, lane, fNB);
#pragma unroll 8
  for (int e = 0; e < ENF; ++e) acc += nd[wv][e] * load1(node_W, e * FF + lane, fNW);
  nf[bi * FF + lane] = acc;
  nf_s[wv][lane] = acc;
  __syncthreads();
  if (lane < HH) {
    float s = 0.f;
#pragma unroll
    for (int k = 0; k < FF; ++k) s += nf_s[wv][k] * load1(att_W, k * HH + lane, fAW);
    q[bi * HH + lane] = s;
    q_s[wv][lane] = s;
  }
  __syncthreads();
  {
    float s = 0.f;
#pragma unroll
    for (int h = 0; h < HH; ++h) s += load1(att_W, lane * HH + h, fAW) * q_s[wv][h];
    v[bi * FF + lane] = s * INV_SQRT8;       // fold 1/sqrt(D_EDGE)
  }
  if (bi == 0) {                             // wave 0 of block 0 only; no barriers inside
    for (int idx = lane; idx < EEF * FF; idx += 64)
      eWf[idx] = load1(edge_W, idx, fEW);
    ebf[lane] = load1(edge_b, lane, fEB);
    // M[c][h] = sum_k edge_W[c,k] * att_W[k,h]   (lane owns row c = lane)
    float mrow[HH];
#pragma unroll
    for (int h = 0; h < HH; ++h) mrow[h] = 0.f;
    for (int k = 0; k < FF; ++k) {
      float w = load1(edge_W, (size_t)lane * FF + k, fEW);
#pragma unroll
      for (int h = 0; h < HH; ++h) mrow[h] += w * load1(att_W, k * HH + h, fAW);
    }
#pragma unroll
    for (int h = 0; h < HH; ++h) Mf[lane * HH + h] = mrow[h];
    // pack B fragments for mfma_f32_16x16x32_bf16, split-precision hi/lo.
    // B[k][n]: lane holds n=l&15, k=(l>>4)*8+j; frag f = ks*4+nt (ks: k-block of 32).
    uint32_t* dH = (uint32_t*)(g_ws + WS_EWFH);
    uint32_t* dL = (uint32_t*)(g_ws + WS_EWFL);
#pragma unroll
    for (int ks = 0; ks < 2; ++ks) {
#pragma unroll
      for (int nt = 0; nt < 4; ++nt) {
        const int f = ks * 4 + nt;
        const int n = nt * 16 + (lane & 15);
        const int e0 = ks * 32 + ((lane >> 4) << 3);
#pragma unroll
        for (int jj = 0; jj < 4; ++jj) {
          float w0 = load1(edge_W, (size_t)(e0 + 2 * jj) * FF + n, fEW);
          float w1 = load1(edge_W, (size_t)(e0 + 2 * jj + 1) * FF + n, fEW);
          uint32_t hi, lo;
          split2(w0, w1, hi, lo);
          dH[(f * 64 + lane) * 4 + jj] = hi;
          dL[(f * 64 + lane) * 4 + jj] = lo;
        }
      }
    }
  }
}

// ---------------- K2s: per-node-row softmax stats (m, 1/S) ----------------
__global__ __launch_bounds__(256) void k2_stats() {
  const float* ws_q = g_ws + WS_Q;
  float* st = g_ws + WS_STATS;
  const int bi = blockIdx.x;          // b*N + i
  const int b  = bi >> 9;
  const int t  = threadIdx.x;
  __shared__ float red[4];
  __shared__ float red2[4];
  const float* qi = ws_q + bi * HH;
  const float q0 = qi[0], q1 = qi[1], q2 = qi[2], q3 = qi[3];
  const float q4 = qi[4], q5 = qi[5], q6 = qi[6], q7 = qi[7];
  const float* qb = ws_q + ((size_t)(b << 9)) * HH;
  const int j0 = t, j1 = t + 256;
  const float* qa = qb + j0 * HH;
  float s0 = (q0*qa[0]+q1*qa[1]+q2*qa[2]+q3*qa[3]+q4*qa[4]+q5*qa[5]+q6*qa[6]+q7*qa[7]) * INV_SQRT8;
  const float* qc = qb + j1 * HH;
  float s1 = (q0*qc[0]+q1*qc[1]+q2*qc[2]+q3*qc[3]+q4*qc[4]+q5*qc[5]+q6*qc[6]+q7*qc[7]) * INV_SQRT8;
  float m = fmaxf(s0, s1);
  for (int o = 32; o > 0; o >>= 1) m = fmaxf(m, __shfl_xor(m, o));
  if ((t & 63) == 0) red[t >> 6] = m;
  __syncthreads();
  m = fmaxf(fmaxf(red[0], red[1]), fmaxf(red[2], red[3]));
  float p0 = expf(s0 - m), p1 = expf(s1 - m);
  float s = p0 + p1;
  for (int o = 32; o > 0; o >>= 1) s += __shfl_xor(s, o);
  if ((t & 63) == 0) red2[t >> 6] = s;
  __syncthreads();
  if (t == 0) {
    st[bi * 2]     = m;
    st[bi * 2 + 1] = 1.0f / (red2[0] + red2[1] + red2[2] + red2[3]);
  }
}

// ---------------- K4 (bf16 edges): score-first, softmax, tiled MFMA ----------------
__global__ __launch_bounds__(512, 4) void k4_bf16(
    const void* __restrict__ edges, float* __restrict__ out) {
  if (g_ws[WS_FLAG + 0] != 0.0f) return;     // edges are f32 -> k4_f32 handles
  const float* nf  = g_ws + WS_NF;
  const float* qws = g_ws + WS_Q;
  const float* ebf = g_ws + WS_EB;
  const float* Mf  = g_ws + WS_M;
  const float* st  = g_ws + WS_STATS;
  const int bi = blockIdx.x;          // b*N + i
  const int t  = threadIdx.x;         // 0..511
  const int lane = t & 63;
  const int wv = t >> 6;              // wave 0..7, owns rows wv*64..wv*64+63

  __shared__ float wn_s[NN];
  __shared__ float wcol_s[NN];
  __shared__ float se_s[NN];
  __shared__ float u_s[EEF];
  __shared__ float nfi_s[FF];
  __shared__ float red[8], red2[8];
  __shared__ float aef_w[8][FF];
  __shared__ float awn_w[8][FF];

  if (t < FF) nfi_s[t] = nf[bi * FF + t];
  if (t < EEF) {
    const float* qi = qws + bi * HH;
    const float* mr = Mf + t * HH;
    float s = 0.f;
#pragma unroll
    for (int h = 0; h < HH; ++h) s += mr[h] * qi[h];
    u_s[t] = s * INV_SQRT8;
  }
  const float m_i   = st[bi * 2];
  const float inv_i = st[bi * 2 + 1];
  const float* qi = qws + bi * HH;
  const float q0 = qi[0], q1 = qi[1], q2 = qi[2], q3 = qi[3];
  const float q4 = qi[4], q5 = qi[5], q6 = qi[6], q7 = qi[7];
  const int bbase = (bi >> 9) << 9;
  const float* qt = qws + ((size_t)(bbase + t)) * HH;
  const float s_t = (q0*qt[0]+q1*qt[1]+q2*qt[2]+q3*qt[3]
                    +q4*qt[4]+q5*qt[5]+q6*qt[6]+q7*qt[7]) * INV_SQRT8;
  wn_s[t] = expf(s_t - m_i) * inv_i;
  const float2 stt = ((const float2*)st)[bbase + t];
  wcol_s[t] = expf(s_t - stt.x) * stt.y;
  __syncthreads();                                      // B0

  {
    float u8[8];
#pragma unroll
    for (int c = 0; c < 8; ++c) u8[c] = u_s[8 * (lane & 7) + c];
    const uint4* ep = (const uint4*)((const uint16_t*)edges
                      + ((size_t)bi * NN + wv * 64) * EEF);
#pragma unroll
    for (int it = 0; it < 8; ++it) {
      const int r = it * 8 + (lane >> 3);
      uint4 x = ep[(size_t)r * 8 + (lane & 7)];
      float p = __uint_as_float(x.x << 16)          * u8[0]
              + __uint_as_float(x.x & 0xFFFF0000u)  * u8[1]
              + __uint_as_float(x.y << 16)          * u8[2]
              + __uint_as_float(x.y & 0xFFFF0000u)  * u8[3]
              + __uint_as_float(x.z << 16)          * u8[4]
              + __uint_as_float(x.z & 0xFFFF0000u)  * u8[5]
              + __uint_as_float(x.w << 16)          * u8[6]
              + __uint_as_float(x.w & 0xFFFF0000u)  * u8[7];
      p += __shfl_xor(p, 1); p += __shfl_xor(p, 2); p += __shfl_xor(p, 4);
      if ((lane & 7) == 0) se_s[wv * 64 + r] = p;
    }
  }
  __syncthreads();                                      // B1

  const float sev = se_s[t];
  float m = sev;
  for (int o = 32; o > 0; o >>= 1) m = fmaxf(m, __shfl_xor(m, o));
  if (lane == 0) red[wv] = m;
  __syncthreads();                                      // B2
  m = red[0];
#pragma unroll
  for (int w = 1; w < 8; ++w) m = fmaxf(m, red[w]);
  const float p = expf(sev - m);
  float ssum = p;
  for (int o = 32; o > 0; o >>= 1) ssum += __shfl_xor(ssum, o);
  if (lane == 0) red2[wv] = ssum;
  se_s[t] = p;
  __syncthreads();                                      // B2b
  float tot = red2[0];
#pragma unroll
  for (int w = 1; w < 8; ++w) tot += red2[w];
  const float inv_tot = 1.0f / tot;

  short8 bh[8], bl[8];
#pragma unroll
  for (int f = 0; f < 8; ++f) {
    uint4 h = ((const uint4*)(g_ws + WS_EWFH))[f * 64 + lane];
    uint4 l = ((const uint4*)(g_ws + WS_EWFL))[f * 64 + lane];
    bh[f] = *(const short8*)&h;
    bl[f] = *(const short8*)&l;
  }
  float eb_n[4], nf_v[4];
#pragma unroll
  for (int nt = 0; nt < 4; ++nt) {
    eb_n[nt] = ebf[nt * 16 + (lane & 15)];
    nf_v[nt] = nfi_s[nt * 16 + (lane & 15)];
  }
  float aef_v[4] = {0.f, 0.f, 0.f, 0.f};
  const uint16_t* eb16 = (const uint16_t*)edges + ((size_t)bi * NN + wv * 64) * EEF;
  float* oute = out + 65536 + ((size_t)bi * NN + wv * 64) * EEF;
#pragma unroll 1
  for (int mt = 0; mt < 4; ++mt) {
    const uint16_t* ap = eb16 + (size_t)(mt * 16 + (lane & 15)) * EEF + ((lane >> 4) << 3);
    const short8 a0 = *(const short8*)(ap);
    const short8 a1 = *(const short8*)(ap + 32);
    floatx4 acc[4];
#pragma unroll
    for (int nt = 0; nt < 4; ++nt)
      acc[nt] = (floatx4){eb_n[nt], eb_n[nt], eb_n[nt], eb_n[nt]};
#pragma unroll
    for (int nt = 0; nt < 4; ++nt) {
      floatx4 c = acc[nt];
      c = __builtin_amdgcn_mfma_f32_16x16x32_bf16(a0, bh[nt],     c, 0, 0, 0);
      c = __builtin_amdgcn_mfma_f32_16x16x32_bf16(a1, bh[4 + nt], c, 0, 0, 0);
      c = __builtin_amdgcn_mfma_f32_16x16x32_bf16(a0, bl[nt],     c, 0, 0, 0);
      c = __builtin_amdgcn_mfma_f32_16x16x32_bf16(a1, bl[4 + nt], c, 0, 0, 0);
      acc[nt] = c;
    }
#pragma unroll
    for (int r = 0; r < 4; ++r) {
      const int row = mt * 16 + ((lane >> 4) << 2) + r;
      const float we = se_s[wv * 64 + row] * inv_tot;
      const float wnr = wn_s[wv * 64 + row];
      const float onewe = 1.0f + we;
#pragma unroll
      for (int nt = 0; nt < 4; ++nt) {
        const float c = acc[nt][r];
        oute[(size_t)row * EEF + nt * 16 + (lane & 15)] = elu(c * onewe + wnr * nf_v[nt]);
        aef_v[nt] = fmaf(we, c, aef_v[nt]);
      }
    }
  }
#pragma unroll
  for (int nt = 0; nt < 4; ++nt) {
    float g = aef_v[nt];
    g += __shfl_xor(g, 16);
    g += __shfl_xor(g, 32);
    if (lane < 16) aef_w[wv][nt * 16 + lane] = g;
  }

  float awn_acc = 0.f;
  {
    const float* nfb = nf + (size_t)bbase * FF;
#pragma unroll 8
    for (int jj = 0; jj < 64; ++jj) {
      const int j = wv * 64 + jj;
      awn_acc = fmaf(wcol_s[j], nfb[(size_t)j * FF + lane], awn_acc);
    }
  }
  awn_w[wv][lane] = awn_acc;
  __syncthreads();                                      // B3

  if (t < FF) {
    float sum = nfi_s[t];
#pragma unroll
    for (int w = 0; w < 8; ++w) sum += aef_w[w][t] + awn_w[w][t];
    out[bi * FF + t] = elu(sum);
  }
}

// ---------------- K4 (f32 edges — the REAL hot path): score-first, softmax,
// then tiled MFMA GEMM in split-bf16 (hi/lo, 3 products -> ~2^-17 rel err).
// Only 16 accumulators live at a time; B frags read from LDS per tile. ----------------
__global__ __launch_bounds__(512, 4) void k4_f32(
    const void* __restrict__ edges, float* __restrict__ out) {
  if (g_ws[WS_FLAG + 0] == 0.0f) return;     // edges are bf16 -> k4_bf16 handles
  const float* nf  = g_ws + WS_NF;
  const float* qws = g_ws + WS_Q;
  const float* ebf = g_ws + WS_EB;
  const float* Mf  = g_ws + WS_M;
  const float* st  = g_ws + WS_STATS;
  const int bi = blockIdx.x;          // b*N + i
  const int t  = threadIdx.x;         // 0..511
  const int lane = t & 63;
  const int wv = t >> 6;              // wave 0..7, owns rows wv*64..wv*64+63

  __shared__ uint4 bH_s[8][64];       // B frags hi, 8KB
  __shared__ uint4 bL_s[8][64];       // B frags lo, 8KB
  __shared__ float wn_s[NN];
  __shared__ float wcol_s[NN];
  __shared__ float se_s[NN];
  __shared__ float u_s[EEF];
  __shared__ float nfi_s[FF];
  __shared__ float red[8], red2[8];
  __shared__ float aef_w[8][FF];
  __shared__ float awn_w[8][FF];

  ((uint4*)bH_s)[t] = ((const uint4*)(g_ws + WS_EWFH))[t];
  ((uint4*)bL_s)[t] = ((const uint4*)(g_ws + WS_EWFL))[t];
  if (t < FF) nfi_s[t] = nf[bi * FF + t];
  if (t < EEF) {
    const float* qi2 = qws + bi * HH;  // uniform -> s_load
    const float* mr = Mf + t * HH;
    float s = 0.f;
#pragma unroll
    for (int h = 0; h < HH; ++h) s += mr[h] * qi2[h];
    u_s[t] = s * INV_SQRT8;            // u = (edge_W @ att_W @ q_i)/sqrt(8)
  }
  // node scores from q (symmetric sn): wn row + column
  const float m_i   = st[bi * 2];
  const float inv_i = st[bi * 2 + 1];
  const float* qi = qws + bi * HH;
  const float q0 = qi[0], q1 = qi[1], q2 = qi[2], q3 = qi[3];
  const float q4 = qi[4], q5 = qi[5], q6 = qi[6], q7 = qi[7];
  const int bbase = (bi >> 9) << 9;
  const float* qt = qws + ((size_t)(bbase + t)) * HH;
  const float s_t = (q0*qt[0]+q1*qt[1]+q2*qt[2]+q3*qt[3]
                    +q4*qt[4]+q5*qt[5]+q6*qt[6]+q7*qt[7]) * INV_SQRT8;
  wn_s[t] = expf(s_t - m_i) * inv_i;                    // wn[i, t]
  const float2 stt = ((const float2*)st)[bbase + t];
  wcol_s[t] = expf(s_t - stt.x) * stt.y;                // wn[t, i]
  __syncthreads();                                      // B0

  // ---- pass A: se_j = e_row_j . u  (f32, 16 lanes per row, full precision) ----
  {
    float u4[4];
#pragma unroll
    for (int c = 0; c < 4; ++c) u4[c] = u_s[4 * (lane & 15) + c];
    const float4* ep = (const float4*)edges + ((size_t)bi * NN + wv * 64) * 16;
#pragma unroll 4
    for (int it = 0; it < 16; ++it) {
      const int r = it * 4 + (lane >> 4);
      float4 x = ep[(size_t)r * 16 + (lane & 15)];
      float p = x.x * u4[0] + x.y * u4[1] + x.z * u4[2] + x.w * u4[3];
      p += __shfl_xor(p, 1); p += __shfl_xor(p, 2);
      p += __shfl_xor(p, 4); p += __shfl_xor(p, 8);
      if ((lane & 15) == 0) se_s[wv * 64 + r] = p;
    }
  }
  __syncthreads();                                      // B1

  // ---- softmax over 512 rows ----
  const float sev = se_s[t];
  float m = sev;
  for (int o = 32; o > 0; o >>= 1) m = fmaxf(m, __shfl_xor(m, o));
  if (lane == 0) red[wv] = m;
  __syncthreads();                                      // B2
  m = red[0];
#pragma unroll
  for (int w = 1; w < 8; ++w) m = fmaxf(m, red[w]);
  const float p = expf(sev - m);
  float ssum = p;
  for (int o = 32; o > 0; o >>= 1) ssum += __shfl_xor(ssum, o);
  if (lane == 0) red2[wv] = ssum;
  se_s[t] = p;
  __syncthreads();                                      // B2b
  float tot = red2[0];
#pragma unroll
  for (int w = 1; w < 8; ++w) tot += red2[w];
  const float inv_tot = 1.0f / tot;

  // ---- pass B: tiled MFMA GEMM (split-bf16) + fused epilogue (16 rows/tile) ----
  // A[i][k]: lane holds i=lane&15, k=(lane>>4)*8+j. C: col=lane&15, row=(lane>>4)*4+r.
  float eb_n[4], nf_v[4];
#pragma unroll
  for (int nt = 0; nt < 4; ++nt) {
    eb_n[nt] = ebf[nt * 16 + (lane & 15)];
    nf_v[nt] = nfi_s[nt * 16 + (lane & 15)];
  }
  float aef_v[4] = {0.f, 0.f, 0.f, 0.f};
  const float* ef32 = (const float*)edges + ((size_t)bi * NN + wv * 64) * EEF;
  float* oute = out + 65536 + ((size_t)bi * NN + wv * 64) * EEF;
#pragma unroll 1
  for (int mt = 0; mt < 4; ++mt) {
    const float* ap = ef32 + (size_t)(mt * 16 + (lane & 15)) * EEF + ((lane >> 4) << 3);
    const float4 x0 = *(const float4*)(ap);
    const float4 x1 = *(const float4*)(ap + 4);
    const float4 x2 = *(const float4*)(ap + 32);
    const float4 x3 = *(const float4*)(ap + 36);
    // convert to split-bf16 A fragments (k 0..31 -> a0, k 32..63 -> a1)
    union { uint32_t u[4]; short8 s; } a0h, a0l, a1h, a1l;
    split2(x0.x, x0.y, a0h.u[0], a0l.u[0]);
    split2(x0.z, x0.w, a0h.u[1], a0l.u[1]);
    split2(x1.x, x1.y, a0h.u[2], a0l.u[2]);
    split2(x1.z, x1.w, a0h.u[3], a0l.u[3]);
    split2(x2.x, x2.y, a1h.u[0], a1l.u[0]);
    split2(x2.z, x2.w, a1h.u[1], a1l.u[1]);
    split2(x3.x, x3.y, a1h.u[2], a1l.u[2]);
    split2(x3.z, x3.w, a1h.u[3], a1l.u[3]);
    floatx4 acc[4];
#pragma unroll
    for (int nt = 0; nt < 4; ++nt) {
      const uint4 h0 = bH_s[nt][lane];
      const uint4 h1 = bH_s[4 + nt][lane];
      const uint4 l0 = bL_s[nt][lane];
      const uint4 l1 = bL_s[4 + nt][lane];
      floatx4 c = (floatx4){eb_n[nt], eb_n[nt], eb_n[nt], eb_n[nt]};
      c = __builtin_amdgcn_mfma_f32_16x16x32_bf16(a0h.s, *(const short8*)&h0, c, 0, 0, 0);
      c = __builtin_amdgcn_mfma_f32_16x16x32_bf16(a1h.s, *(const short8*)&h1, c, 0, 0, 0);
      c = __builtin_amdgcn_mfma_f32_16x16x32_bf16(a0h.s, *(const short8*)&l0, c, 0, 0, 0);
      c = __builtin_amdgcn_mfma_f32_16x16x32_bf16(a1h.s, *(const short8*)&l1, c, 0, 0, 0);
      c = __builtin_amdgcn_mfma_f32_16x16x32_bf16(a0l.s, *(const short8*)&h0, c, 0, 0, 0);
      c = __builtin_amdgcn_mfma_f32_16x16x32_bf16(a1l.s, *(const short8*)&h1, c, 0, 0, 0);
      acc[nt] = c;
    }
#pragma unroll
    for (int r = 0; r < 4; ++r) {
      const int row = mt * 16 + ((lane >> 4) << 2) + r;
      const float we = se_s[wv * 64 + row] * inv_tot;
      const float wnr = wn_s[wv * 64 + row];
      const float onewe = 1.0f + we;
#pragma unroll
      for (int nt = 0; nt < 4; ++nt) {
        const float c = acc[nt][r];
        oute[(size_t)row * EEF + nt * 16 + (lane & 15)] = elu(c * onewe + wnr * nf_v[nt]);
        aef_v[nt] = fmaf(we, c, aef_v[nt]);
      }
    }
  }
#pragma unroll
  for (int nt = 0; nt < 4; ++nt) {
    float g = aef_v[nt];
    g += __shfl_xor(g, 16);
    g += __shfl_xor(g, 32);
    if (lane < 16) aef_w[wv][nt * 16 + lane] = g;
  }

  // ---- awn[b,i,k] = sum_j wn[b,j,i]*nf[b,j,k]  (folded k3; nf is L2-hot) ----
  float awn_acc = 0.f;
  {
    const float* nfb = nf + (size_t)bbase * FF;
#pragma unroll 8
    for (int jj = 0; jj < 64; ++jj) {
      const int j = wv * 64 + jj;
      awn_acc = fmaf(wcol_s[j], nfb[(size_t)j * FF + lane], awn_acc);
    }
  }
  awn_w[wv][lane] = awn_acc;
  __syncthreads();                                      // B3

  if (t < FF) {
    float sum = nfi_s[t];
#pragma unroll
    for (int w = 0; w < 8; ++w) sum += aef_w[w][t] + awn_w[w][t];
    out[bi * FF + t] = elu(sum);
  }
}

extern "C" void kernel_launch(void* const* d_in, const int* in_sizes, int n_in,
                              void* d_out, int out_size, void* d_ws, size_t ws_size,
                              hipStream_t stream) {
  // Identify inputs by element count (robust to mask-dropping / reordering).
  const void* nodes = nullptr; const void* edges = nullptr;
  const void* node_W = nullptr; const void* node_b = nullptr;
  const void* edge_W = nullptr; const void* edge_b = nullptr;
  const void* att_W = nullptr;
  int bias_seen = 0;
  for (int i = 0; i < n_in; ++i) {
    switch (in_sizes[i]) {
      case 33554432: edges  = d_in[i]; break;
      case 131072:   nodes  = d_in[i]; break;
      case 8192:     node_W = d_in[i]; break;
      case 4096:     edge_W = d_in[i]; break;
      case 512:      att_W  = d_in[i]; break;
      case 64:       if (bias_seen++ == 0) node_b = d_in[i]; else edge_b = d_in[i]; break;
      default: break;  // mask or scalars: unused
    }
  }
  float* out = (float*)d_out;

  k0_detect<<<dim3(7), dim3(256), 0, stream>>>(
      (const uint16_t*)edges, 33554432, (const uint16_t*)nodes, 131072,
      (const uint16_t*)node_W, 8192, (const uint16_t*)node_b, 64,
      (const uint16_t*)edge_W, 4096, (const uint16_t*)edge_b, 64,
      (const uint16_t*)att_W, 512);
  k1_nf_q_v<<<dim3(BB * NN / 4), dim3(256), 0, stream>>>(nodes, node_W, node_b,
                                                         att_W, edge_W, edge_b);
  k2_stats<<<dim3(BB * NN), dim3(256), 0, stream>>>();
  k4_bf16<<<dim3(BB * NN), dim3(512), 0, stream>>>(edges, out);
  k4_f32<<<dim3(BB * NN), dim3(512), 0, stream>>>(edges, out);
}

// Round 7
// 323.129 us; speedup vs baseline: 2.1229x; 1.1407x over previous
//
#include <hip/hip_runtime.h>
#include <stdint.h>

#define BB 2
#define NN 512
#define ENF 128
#define EEF 64
#define FF 64
#define HH 8

// static scratch offsets (floats)
#define WS_NF    0        // [B*N*64]   = 65536
#define WS_Q     65536    // [B*N*8]    = 8192
#define WS_V     73728    // [B*N*64]   = 65536  (v = att_W@q * 1/sqrt(8); bf16 path)
#define WS_EW    139264   // [64*64]    = 4096   (f32 weights)
#define WS_EB    143360   // [64]
#define WS_M     143424   // [64*8]     = 512    (M = edge_W @ att_W)
#define WS_STATS 143936   // [B*N*2]    = 2048   (m, 1/S per node row)
#define WS_FLAG  145984   // [7] flags + 1 pad
#define WS_EWFH  145992   // [8 frag][64 lane][4 u32] bf16-hi B fragments = 4096
#define WS_EWFL  150088   // same, bf16-lo residual                      = 4096
#define WS_TOTAL 154184
// flag index: 0=edges 1=nodes 2=node_W 3=node_b 4=edge_W 5=edge_b 6=att_W

__device__ __align__(16) float g_ws[WS_TOTAL];

using short8  = __attribute__((ext_vector_type(8))) short;
using floatx4 = __attribute__((ext_vector_type(4))) float;

__device__ __forceinline__ float bf2f(uint16_t u) {
  return __uint_as_float(((uint32_t)u) << 16);
}
__device__ __forceinline__ uint16_t f2bf(float f) {   // RNE f32->bf16
  uint32_t u = __float_as_uint(f);
  return (uint16_t)((u + 0x7FFFu + ((u >> 16) & 1u)) >> 16);
}
// split two f32 into packed bf16 hi pair + bf16 residual-lo pair
__device__ __forceinline__ void split2(float f0, float f1, uint32_t& hi, uint32_t& lo) {
  uint16_t h0 = f2bf(f0), h1 = f2bf(f1);
  float r0 = f0 - bf2f(h0), r1 = f1 - bf2f(h1);
  uint16_t l0 = f2bf(r0), l1 = f2bf(r1);
  hi = (uint32_t)h0 | ((uint32_t)h1 << 16);
  lo = (uint32_t)l0 | ((uint32_t)l1 << 16);
}
__device__ __forceinline__ float load1(const void* p, size_t i, bool isf32) {
  return isf32 ? ((const float*)p)[i] : bf2f(((const uint16_t*)p)[i]);
}
__device__ __forceinline__ float elu(float x) {
  return x > 0.f ? x : expf(x) - 1.0f;
}

constexpr float INV_SQRT8 = 0.35355339059327373f;

// ------------- K0: per-array dtype detection (f32 vs bf16 in memory) -------------
__global__ __launch_bounds__(256) void k0_detect(
    const uint16_t* p0, int c0, const uint16_t* p1, int c1,
    const uint16_t* p2, int c2, const uint16_t* p3, int c3,
    const uint16_t* p4, int c4, const uint16_t* p5, int c5,
    const uint16_t* p6, int c6) {
  const uint16_t* ptrs[7] = {p0, p1, p2, p3, p4, p5, p6};
  const int cnts[7] = {c0, c1, c2, c3, c4, c5, c6};
  const int a = blockIdx.x;
  const uint16_t* e = ptrs[a];
  int S = cnts[a] / 2; if (S > 2048) S = 2048;
  const int t = threadIdx.x;
  int hi = 0, z0 = 0, nz1 = 0;
  for (int i = t; i < S; i += 256) {
    uint16_t h0 = e[2 * i], h1 = e[2 * i + 1];
    if (((h0 >> 7) & 0xFF) >= 0x90) hi++;
    if (h0 == 0) z0++;
    if (h1 != 0) nz1++;
  }
  for (int o = 32; o > 0; o >>= 1) {
    hi += __shfl_xor(hi, o); z0 += __shfl_xor(z0, o); nz1 += __shfl_xor(nz1, o);
  }
  __shared__ int r[3][4];
  if ((t & 63) == 0) { int w = t >> 6; r[0][w] = hi; r[1][w] = z0; r[2][w] = nz1; }
  __syncthreads();
  if (t == 0) {
    int H  = r[0][0] + r[0][1] + r[0][2] + r[0][3];
    int Z  = r[1][0] + r[1][1] + r[1][2] + r[1][3];
    int NZ = r[2][0] + r[2][1] + r[2][2] + r[2][3];
    g_ws[WS_FLAG + a] =
        (H > S / 16 || (Z * 8 > S * 3 && NZ * 8 > S * 3)) ? 1.0f : 0.0f;
  }
}

// ---- K1: nf, q, v (+ weight prep, distributed over block 0's four waves) ----
__global__ __launch_bounds__(256) void k1_nf_q_v(
    const void* __restrict__ nodes, const void* __restrict__ node_W,
    const void* __restrict__ node_b, const void* __restrict__ att_W,
    const void* __restrict__ edge_W, const void* __restrict__ edge_b) {
  float* nf  = g_ws + WS_NF;
  float* q   = g_ws + WS_Q;
  float* v   = g_ws + WS_V;
  float* eWf = g_ws + WS_EW;
  float* ebf = g_ws + WS_EB;
  float* Mf  = g_ws + WS_M;
  const float* fl = g_ws + WS_FLAG;
  const bool fNodes = fl[1] != 0.f, fNW = fl[2] != 0.f, fNB = fl[3] != 0.f;
  const bool fEW = fl[4] != 0.f, fEB = fl[5] != 0.f, fAW = fl[6] != 0.f;
  const int t    = threadIdx.x;
  const int lane = t & 63;
  const int wv   = t >> 6;
  const int bi   = blockIdx.x * 4 + wv;      // b*N + n
  __shared__ float nd[4][ENF];
  __shared__ float nf_s[4][FF];
  __shared__ float q_s[4][HH];
  nd[wv][lane]      = load1(nodes, (size_t)bi * ENF + lane, fNodes);
  nd[wv][lane + 64] = load1(nodes, (size_t)bi * ENF + lane + 64, fNodes);
  __syncthreads();
  float acc = load1(node_b, lane, fNB);
#pragma unroll 8
  for (int e = 0; e < ENF; ++e) acc += nd[wv][e] * load1(node_W, e * FF + lane, fNW);
  nf[bi * FF + lane] = acc;
  nf_s[wv][lane] = acc;
  __syncthreads();
  if (lane < HH) {
    float s = 0.f;
#pragma unroll
    for (int k = 0; k < FF; ++k) s += nf_s[wv][k] * load1(att_W, k * HH + lane, fAW);
    q[bi * HH + lane] = s;
    q_s[wv][lane] = s;
  }
  __syncthreads();
  {
    float s = 0.f;
#pragma unroll
    for (int h = 0; h < HH; ++h) s += load1(att_W, lane * HH + h, fAW) * q_s[wv][h];
    v[bi * FF + lane] = s * INV_SQRT8;       // fold 1/sqrt(D_EDGE)
  }
  if (blockIdx.x == 0) {                     // weight prep, one task per wave
    if (wv == 0) {
      for (int idx = lane; idx < EEF * FF; idx += 64)
        eWf[idx] = load1(edge_W, idx, fEW);
      ebf[lane] = load1(edge_b, lane, fEB);
    } else if (wv == 1) {
      // M[c][h] = sum_k edge_W[c,k] * att_W[k,h]   (lane owns row c = lane)
      float mrow[HH];
#pragma unroll
      for (int h = 0; h < HH; ++h) mrow[h] = 0.f;
      for (int k = 0; k < FF; ++k) {
        float w = load1(edge_W, (size_t)lane * FF + k, fEW);
#pragma unroll
        for (int h = 0; h < HH; ++h) mrow[h] += w * load1(att_W, k * HH + h, fAW);
      }
#pragma unroll
      for (int h = 0; h < HH; ++h) Mf[lane * HH + h] = mrow[h];
    } else {
      // pack B fragments for mfma_f32_16x16x32_bf16, split hi/lo.
      // B[k][n]: lane holds n=l&15, k=(l>>4)*8+j; frag f = ks*4+nt. wave2: ks=0, wave3: ks=1.
      const int ks = wv - 2;
      uint32_t* dH = (uint32_t*)(g_ws + WS_EWFH);
      uint32_t* dL = (uint32_t*)(g_ws + WS_EWFL);
#pragma unroll
      for (int nt = 0; nt < 4; ++nt) {
        const int f = ks * 4 + nt;
        const int n = nt * 16 + (lane & 15);
        const int e0 = ks * 32 + ((lane >> 4) << 3);
#pragma unroll
        for (int jj = 0; jj < 4; ++jj) {
          float w0 = load1(edge_W, (size_t)(e0 + 2 * jj) * FF + n, fEW);
          float w1 = load1(edge_W, (size_t)(e0 + 2 * jj + 1) * FF + n, fEW);
          uint32_t hi, lo;
          split2(w0, w1, hi, lo);
          dH[(f * 64 + lane) * 4 + jj] = hi;
          dL[(f * 64 + lane) * 4 + jj] = lo;
        }
      }
    }
  }
}

// ---------------- K2s: per-node-row softmax stats (m, 1/S) ----------------
__global__ __launch_bounds__(256) void k2_stats() {
  const float* ws_q = g_ws + WS_Q;
  float* st = g_ws + WS_STATS;
  const int bi = blockIdx.x;          // b*N + i
  const int b  = bi >> 9;
  const int t  = threadIdx.x;
  __shared__ float red[4];
  __shared__ float red2[4];
  const float* qi = ws_q + bi * HH;
  const float q0 = qi[0], q1 = qi[1], q2 = qi[2], q3 = qi[3];
  const float q4 = qi[4], q5 = qi[5], q6 = qi[6], q7 = qi[7];
  const float* qb = ws_q + ((size_t)(b << 9)) * HH;
  const int j0 = t, j1 = t + 256;
  const float* qa = qb + j0 * HH;
  float s0 = (q0*qa[0]+q1*qa[1]+q2*qa[2]+q3*qa[3]+q4*qa[4]+q5*qa[5]+q6*qa[6]+q7*qa[7]) * INV_SQRT8;
  const float* qc = qb + j1 * HH;
  float s1 = (q0*qc[0]+q1*qc[1]+q2*qc[2]+q3*qc[3]+q4*qc[4]+q5*qc[5]+q6*qc[6]+q7*qc[7]) * INV_SQRT8;
  float m = fmaxf(s0, s1);
  for (int o = 32; o > 0; o >>= 1) m = fmaxf(m, __shfl_xor(m, o));
  if ((t & 63) == 0) red[t >> 6] = m;
  __syncthreads();
  m = fmaxf(fmaxf(red[0], red[1]), fmaxf(red[2], red[3]));
  float p0 = expf(s0 - m), p1 = expf(s1 - m);
  float s = p0 + p1;
  for (int o = 32; o > 0; o >>= 1) s += __shfl_xor(s, o);
  if ((t & 63) == 0) red2[t >> 6] = s;
  __syncthreads();
  if (t == 0) {
    st[bi * 2]     = m;
    st[bi * 2 + 1] = 1.0f / (red2[0] + red2[1] + red2[2] + red2[3]);
  }
}

// ---------------- K4 (bf16 edges): score-first, softmax, tiled MFMA (r6 structure) ----------------
__global__ __launch_bounds__(512, 4) void k4_bf16(
    const void* __restrict__ edges, float* __restrict__ out) {
  if (g_ws[WS_FLAG + 0] != 0.0f) return;     // edges are f32 -> k4_f32 handles
  const float* nf  = g_ws + WS_NF;
  const float* qws = g_ws + WS_Q;
  const float* ebf = g_ws + WS_EB;
  const float* Mf  = g_ws + WS_M;
  const float* st  = g_ws + WS_STATS;
  const int bi = blockIdx.x;
  const int t  = threadIdx.x;
  const int lane = t & 63;
  const int wv = t >> 6;

  __shared__ float wn_s[NN];
  __shared__ float wcol_s[NN];
  __shared__ float se_s[NN];
  __shared__ float u_s[EEF];
  __shared__ float nfi_s[FF];
  __shared__ float red[8], red2[8];
  __shared__ float aef_w[8][FF];
  __shared__ float awn_w[8][FF];

  if (t < FF) nfi_s[t] = nf[bi * FF + t];
  if (t < EEF) {
    const float* qi = qws + bi * HH;
    const float* mr = Mf + t * HH;
    float s = 0.f;
#pragma unroll
    for (int h = 0; h < HH; ++h) s += mr[h] * qi[h];
    u_s[t] = s * INV_SQRT8;
  }
  const float m_i   = st[bi * 2];
  const float inv_i = st[bi * 2 + 1];
  const float* qi = qws + bi * HH;
  const float q0 = qi[0], q1 = qi[1], q2 = qi[2], q3 = qi[3];
  const float q4 = qi[4], q5 = qi[5], q6 = qi[6], q7 = qi[7];
  const int bbase = (bi >> 9) << 9;
  const float* qt = qws + ((size_t)(bbase + t)) * HH;
  const float s_t = (q0*qt[0]+q1*qt[1]+q2*qt[2]+q3*qt[3]
                    +q4*qt[4]+q5*qt[5]+q6*qt[6]+q7*qt[7]) * INV_SQRT8;
  wn_s[t] = expf(s_t - m_i) * inv_i;
  const float2 stt = ((const float2*)st)[bbase + t];
  wcol_s[t] = expf(s_t - stt.x) * stt.y;
  __syncthreads();

  {
    float u8[8];
#pragma unroll
    for (int c = 0; c < 8; ++c) u8[c] = u_s[8 * (lane & 7) + c];
    const uint4* ep = (const uint4*)((const uint16_t*)edges
                      + ((size_t)bi * NN + wv * 64) * EEF);
#pragma unroll
    for (int it = 0; it < 8; ++it) {
      const int r = it * 8 + (lane >> 3);
      uint4 x = ep[(size_t)r * 8 + (lane & 7)];
      float p = __uint_as_float(x.x << 16)          * u8[0]
              + __uint_as_float(x.x & 0xFFFF0000u)  * u8[1]
              + __uint_as_float(x.y << 16)          * u8[2]
              + __uint_as_float(x.y & 0xFFFF0000u)  * u8[3]
              + __uint_as_float(x.z << 16)          * u8[4]
              + __uint_as_float(x.z & 0xFFFF0000u)  * u8[5]
              + __uint_as_float(x.w << 16)          * u8[6]
              + __uint_as_float(x.w & 0xFFFF0000u)  * u8[7];
      p += __shfl_xor(p, 1); p += __shfl_xor(p, 2); p += __shfl_xor(p, 4);
      if ((lane & 7) == 0) se_s[wv * 64 + r] = p;
    }
  }
  __syncthreads();

  const float sev = se_s[t];
  float m = sev;
  for (int o = 32; o > 0; o >>= 1) m = fmaxf(m, __shfl_xor(m, o));
  if (lane == 0) red[wv] = m;
  __syncthreads();
  m = red[0];
#pragma unroll
  for (int w = 1; w < 8; ++w) m = fmaxf(m, red[w]);
  const float p = expf(sev - m);
  float ssum = p;
  for (int o = 32; o > 0; o >>= 1) ssum += __shfl_xor(ssum, o);
  if (lane == 0) red2[wv] = ssum;
  se_s[t] = p;
  __syncthreads();
  float tot = red2[0];
#pragma unroll
  for (int w = 1; w < 8; ++w) tot += red2[w];
  const float inv_tot = 1.0f / tot;

  short8 bh[8], bl[8];
#pragma unroll
  for (int f = 0; f < 8; ++f) {
    uint4 h = ((const uint4*)(g_ws + WS_EWFH))[f * 64 + lane];
    uint4 l = ((const uint4*)(g_ws + WS_EWFL))[f * 64 + lane];
    bh[f] = *(const short8*)&h;
    bl[f] = *(const short8*)&l;
  }
  float eb_n[4], nf_v[4];
#pragma unroll
  for (int nt = 0; nt < 4; ++nt) {
    eb_n[nt] = ebf[nt * 16 + (lane & 15)];
    nf_v[nt] = nfi_s[nt * 16 + (lane & 15)];
  }
  float aef_v[4] = {0.f, 0.f, 0.f, 0.f};
  const uint16_t* eb16 = (const uint16_t*)edges + ((size_t)bi * NN + wv * 64) * EEF;
  float* oute = out + 65536 + ((size_t)bi * NN + wv * 64) * EEF;
#pragma unroll 1
  for (int mt = 0; mt < 4; ++mt) {
    const uint16_t* ap = eb16 + (size_t)(mt * 16 + (lane & 15)) * EEF + ((lane >> 4) << 3);
    const short8 a0 = *(const short8*)(ap);
    const short8 a1 = *(const short8*)(ap + 32);
    floatx4 acc[4];
#pragma unroll
    for (int nt = 0; nt < 4; ++nt)
      acc[nt] = (floatx4){eb_n[nt], eb_n[nt], eb_n[nt], eb_n[nt]};
#pragma unroll
    for (int nt = 0; nt < 4; ++nt) {
      floatx4 c = acc[nt];
      c = __builtin_amdgcn_mfma_f32_16x16x32_bf16(a0, bh[nt],     c, 0, 0, 0);
      c = __builtin_amdgcn_mfma_f32_16x16x32_bf16(a1, bh[4 + nt], c, 0, 0, 0);
      c = __builtin_amdgcn_mfma_f32_16x16x32_bf16(a0, bl[nt],     c, 0, 0, 0);
      c = __builtin_amdgcn_mfma_f32_16x16x32_bf16(a1, bl[4 + nt], c, 0, 0, 0);
      acc[nt] = c;
    }
#pragma unroll
    for (int r = 0; r < 4; ++r) {
      const int row = mt * 16 + ((lane >> 4) << 2) + r;
      const float we = se_s[wv * 64 + row] * inv_tot;
      const float wnr = wn_s[wv * 64 + row];
      const float onewe = 1.0f + we;
#pragma unroll
      for (int nt = 0; nt < 4; ++nt) {
        const float c = acc[nt][r];
        oute[(size_t)row * EEF + nt * 16 + (lane & 15)] = elu(c * onewe + wnr * nf_v[nt]);
        aef_v[nt] = fmaf(we, c, aef_v[nt]);
      }
    }
  }
#pragma unroll
  for (int nt = 0; nt < 4; ++nt) {
    float g = aef_v[nt];
    g += __shfl_xor(g, 16);
    g += __shfl_xor(g, 32);
    if (lane < 16) aef_w[wv][nt * 16 + lane] = g;
  }

  float awn_acc = 0.f;
  {
    const float* nfb = nf + (size_t)bbase * FF;
#pragma unroll 8
    for (int jj = 0; jj < 64; ++jj) {
      const int j = wv * 64 + jj;
      awn_acc = fmaf(wcol_s[j], nfb[(size_t)j * FF + lane], awn_acc);
    }
  }
  awn_w[wv][lane] = awn_acc;
  __syncthreads();

  if (t < FF) {
    float sum = nfi_s[t];
#pragma unroll
    for (int w = 0; w < 8; ++w) sum += aef_w[w][t] + awn_w[w][t];
    out[bi * FF + t] = elu(sum);
  }
}

// ---------------- K4 (f32 edges — hot path): SINGLE edges pass.
// 1024 threads / 16 waves, 32 rows per wave -> only acc[2][4] (32 VGPR) held
// across the softmax barriers; se computed inline from the same f32 loads
// (se = e.u + const, const cancels). B frags in LDS. ----------------
__global__ __launch_bounds__(1024, 1) void k4_f32(
    const void* __restrict__ edges, float* __restrict__ out) {
  if (g_ws[WS_FLAG + 0] == 0.0f) return;     // edges are bf16 -> k4_bf16 handles
  const float* nf  = g_ws + WS_NF;
  const float* qws = g_ws + WS_Q;
  const float* ebf = g_ws + WS_EB;
  const float* Mf  = g_ws + WS_M;
  const float* st  = g_ws + WS_STATS;
  const int bi = blockIdx.x;          // b*N + i
  const int t  = threadIdx.x;         // 0..1023
  const int lane = t & 63;
  const int wv = t >> 6;              // wave 0..15, owns rows wv*32..wv*32+31

  __shared__ uint4 bH_s[8][64];       // B frags hi, 8KB
  __shared__ uint4 bL_s[8][64];       // B frags lo, 8KB
  __shared__ float wn_s[NN];
  __shared__ float wcol_s[NN];
  __shared__ float se_s[NN];
  __shared__ float u_s[EEF];
  __shared__ float nfi_s[FF];
  __shared__ float red[16], red2[16];
  __shared__ float aef_w[16][FF];
  __shared__ float awn_w[16][FF];

  if (t < 512) ((uint4*)bH_s)[t] = ((const uint4*)(g_ws + WS_EWFH))[t];
  else         ((uint4*)bL_s)[t - 512] = ((const uint4*)(g_ws + WS_EWFL))[t - 512];
  if (t < FF) nfi_s[t] = nf[bi * FF + t];
  if (t >= 128 && t < 128 + EEF) {
    const int c = t - 128;
    const float* qi2 = qws + bi * HH;  // uniform -> s_load
    const float* mr = Mf + c * HH;
    float s = 0.f;
#pragma unroll
    for (int h = 0; h < HH; ++h) s += mr[h] * qi2[h];
    u_s[c] = s * INV_SQRT8;            // u = (edge_W @ att_W @ q_i)/sqrt(8)
  }
  // node scores from q (symmetric sn): wn row + column
  const float m_i   = st[bi * 2];
  const float inv_i = st[bi * 2 + 1];
  const float* qi = qws + bi * HH;
  const float q0 = qi[0], q1 = qi[1], q2 = qi[2], q3 = qi[3];
  const float q4 = qi[4], q5 = qi[5], q6 = qi[6], q7 = qi[7];
  const int bbase = (bi >> 9) << 9;
  if (t < NN) {
    const float* qt = qws + ((size_t)(bbase + t)) * HH;
    const float s_t = (q0*qt[0]+q1*qt[1]+q2*qt[2]+q3*qt[3]
                      +q4*qt[4]+q5*qt[5]+q6*qt[6]+q7*qt[7]) * INV_SQRT8;
    wn_s[t] = expf(s_t - m_i) * inv_i;                  // wn[i, t]
    const float2 stt = ((const float2*)st)[bbase + t];
    wcol_s[t] = expf(s_t - stt.x) * stt.y;              // wn[t, i]
  }
  __syncthreads();                                      // B0

  // ---- single pass: load f32 rows once; inline score + split-bf16 MFMA ----
  // A[i][k]: lane holds i=lane&15, k=(lane>>4)*8+j. C: col=lane&15, row=(lane>>4)*4+r.
  float eb_n[4], nf_v[4];
#pragma unroll
  for (int nt = 0; nt < 4; ++nt) {
    eb_n[nt] = ebf[nt * 16 + (lane & 15)];
    nf_v[nt] = nfi_s[nt * 16 + (lane & 15)];
  }
  const int g8 = (lane >> 4) << 3;    // this lane's k-base (0,8,16,24)
  float ulo[8], uhi[8];
#pragma unroll
  for (int j = 0; j < 8; ++j) { ulo[j] = u_s[g8 + j]; uhi[j] = u_s[g8 + 32 + j]; }

  const float* ef32 = (const float*)edges + ((size_t)bi * NN + wv * 32) * EEF;
  floatx4 acc[2][4];
#pragma unroll
  for (int mt = 0; mt < 2; ++mt) {
    const float* ap = ef32 + (size_t)(mt * 16 + (lane & 15)) * EEF + g8;
    const float4 x0 = *(const float4*)(ap);
    const float4 x1 = *(const float4*)(ap + 4);
    const float4 x2 = *(const float4*)(ap + 32);
    const float4 x3 = *(const float4*)(ap + 36);
    // inline edge score partial (f32): se_row = e_row . u  (+const, cancels)
    float p = x0.x*ulo[0] + x0.y*ulo[1] + x0.z*ulo[2] + x0.w*ulo[3]
            + x1.x*ulo[4] + x1.y*ulo[5] + x1.z*ulo[6] + x1.w*ulo[7]
            + x2.x*uhi[0] + x2.y*uhi[1] + x2.z*uhi[2] + x2.w*uhi[3]
            + x3.x*uhi[4] + x3.y*uhi[5] + x3.z*uhi[6] + x3.w*uhi[7];
    p += __shfl_xor(p, 16);
    p += __shfl_xor(p, 32);
    if (lane < 16) se_s[wv * 32 + mt * 16 + lane] = p;
    // convert to split-bf16 A fragments (k 0..31 -> a0, k 32..63 -> a1)
    union { uint32_t u[4]; short8 s; } a0h, a0l, a1h, a1l;
    split2(x0.x, x0.y, a0h.u[0], a0l.u[0]);
    split2(x0.z, x0.w, a0h.u[1], a0l.u[1]);
    split2(x1.x, x1.y, a0h.u[2], a0l.u[2]);
    split2(x1.z, x1.w, a0h.u[3], a0l.u[3]);
    split2(x2.x, x2.y, a1h.u[0], a1l.u[0]);
    split2(x2.z, x2.w, a1h.u[1], a1l.u[1]);
    split2(x3.x, x3.y, a1h.u[2], a1l.u[2]);
    split2(x3.z, x3.w, a1h.u[3], a1l.u[3]);
#pragma unroll
    for (int nt = 0; nt < 4; ++nt) {
      const uint4 h0 = bH_s[nt][lane];
      const uint4 h1 = bH_s[4 + nt][lane];
      const uint4 l0 = bL_s[nt][lane];
      const uint4 l1 = bL_s[4 + nt][lane];
      floatx4 c = (floatx4){eb_n[nt], eb_n[nt], eb_n[nt], eb_n[nt]};
      c = __builtin_amdgcn_mfma_f32_16x16x32_bf16(a0h.s, *(const short8*)&h0, c, 0, 0, 0);
      c = __builtin_amdgcn_mfma_f32_16x16x32_bf16(a1h.s, *(const short8*)&h1, c, 0, 0, 0);
      c = __builtin_amdgcn_mfma_f32_16x16x32_bf16(a0h.s, *(const short8*)&l0, c, 0, 0, 0);
      c = __builtin_amdgcn_mfma_f32_16x16x32_bf16(a1h.s, *(const short8*)&l1, c, 0, 0, 0);
      c = __builtin_amdgcn_mfma_f32_16x16x32_bf16(a0l.s, *(const short8*)&h0, c, 0, 0, 0);
      c = __builtin_amdgcn_mfma_f32_16x16x32_bf16(a1l.s, *(const short8*)&h1, c, 0, 0, 0);
      acc[mt][nt] = c;
    }
  }
  __syncthreads();                                      // B1

  // ---- softmax over 512 rows (threads t<512 own one row each) ----
  const float sev = (t < NN) ? se_s[t] : -3.0e38f;
  float m = sev;
  for (int o = 32; o > 0; o >>= 1) m = fmaxf(m, __shfl_xor(m, o));
  if (lane == 0) red[wv] = m;
  __syncthreads();                                      // B2
  m = red[0];
#pragma unroll
  for (int w = 1; w < 16; ++w) m = fmaxf(m, red[w]);
  const float p = (t < NN) ? expf(sev - m) : 0.f;
  float ssum = p;
  for (int o = 32; o > 0; o >>= 1) ssum += __shfl_xor(ssum, o);
  if (lane == 0) red2[wv] = ssum;
  if (t < NN) se_s[t] = p;
  __syncthreads();                                      // B2b
  float tot = red2[0];
#pragma unroll
  for (int w = 1; w < 16; ++w) tot += red2[w];
  const float inv_tot = 1.0f / tot;

  // ---- epilogue from held accumulators ----
  float aef_v[4] = {0.f, 0.f, 0.f, 0.f};
  float* oute = out + 65536 + ((size_t)bi * NN + wv * 32) * EEF;
#pragma unroll
  for (int mt = 0; mt < 2; ++mt) {
#pragma unroll
    for (int r = 0; r < 4; ++r) {
      const int row = mt * 16 + ((lane >> 4) << 2) + r;
      const float we = se_s[wv * 32 + row] * inv_tot;
      const float wnr = wn_s[wv * 32 + row];
      const float onewe = 1.0f + we;
#pragma unroll
      for (int nt = 0; nt < 4; ++nt) {
        const float c = acc[mt][nt][r];
        oute[(size_t)row * EEF + nt * 16 + (lane & 15)] = elu(c * onewe + wnr * nf_v[nt]);
        aef_v[nt] = fmaf(we, c, aef_v[nt]);
      }
    }
  }
#pragma unroll
  for (int nt = 0; nt < 4; ++nt) {
    float g = aef_v[nt];
    g += __shfl_xor(g, 16);
    g += __shfl_xor(g, 32);
    if (lane < 16) aef_w[wv][nt * 16 + lane] = g;
  }

  // ---- awn[b,i,k] = sum_j wn[b,j,i]*nf[b,j,k]  (32 j's per wave) ----
  float awn_acc = 0.f;
  {
    const float* nfb = nf + (size_t)bbase * FF;
#pragma unroll 8
    for (int jj = 0; jj < 32; ++jj) {
      const int j = wv * 32 + jj;
      awn_acc = fmaf(wcol_s[j], nfb[(size_t)j * FF + lane], awn_acc);
    }
  }
  awn_w[wv][lane] = awn_acc;
  __syncthreads();                                      // B3

  if (t < FF) {
    float sum = nfi_s[t];
#pragma unroll
    for (int w = 0; w < 16; ++w) sum += aef_w[w][t] + awn_w[w][t];
    out[bi * FF + t] = elu(sum);
  }
}

extern "C" void kernel_launch(void* const* d_in, const int* in_sizes, int n_in,
                              void* d_out, int out_size, void* d_ws, size_t ws_size,
                              hipStream_t stream) {
  // Identify inputs by element count (robust to mask-dropping / reordering).
  const void* nodes = nullptr; const void* edges = nullptr;
  const void* node_W = nullptr; const void* node_b = nullptr;
  const void* edge_W = nullptr; const void* edge_b = nullptr;
  const void* att_W = nullptr;
  int bias_seen = 0;
  for (int i = 0; i < n_in; ++i) {
    switch (in_sizes[i]) {
      case 33554432: edges  = d_in[i]; break;
      case 131072:   nodes  = d_in[i]; break;
      case 8192:     node_W = d_in[i]; break;
      case 4096:     edge_W = d_in[i]; break;
      case 512:      att_W  = d_in[i]; break;
      case 64:       if (bias_seen++ == 0) node_b = d_in[i]; else edge_b = d_in[i]; break;
      default: break;  // mask or scalars: unused
    }
  }
  float* out = (float*)d_out;

  k0_detect<<<dim3(7), dim3(256), 0, stream>>>(
      (const uint16_t*)edges, 33554432, (const uint16_t*)nodes, 131072,
      (const uint16_t*)node_W, 8192, (const uint16_t*)node_b, 64,
      (const uint16_t*)edge_W, 4096, (const uint16_t*)edge_b, 64,
      (const uint16_t*)att_W, 512);
  k1_nf_q_v<<<dim3(BB * NN / 4), dim3(256), 0, stream>>>(nodes, node_W, node_b,
                                                         att_W, edge_W, edge_b);
  k2_stats<<<dim3(BB * NN), dim3(256), 0, stream>>>();
  k4_bf16<<<dim3(BB * NN), dim3(512), 0, stream>>>(edges, out);
  k4_f32<<<dim3(BB * NN), dim3(1024), 0, stream>>>(edges, out);
}

// Round 8
// 320.313 us; speedup vs baseline: 2.1416x; 1.0088x over previous
//
#include <hip/hip_runtime.h>
#include <stdint.h>

#define BB 2
#define NN 512
#define ENF 128
#define EEF 64
#define FF 64
#define HH 8

// static scratch offsets (floats)
#define WS_NF    0        // [B*N*64]   = 65536
#define WS_Q     65536    // [B*N*8]    = 8192
#define WS_V     73728    // [B*N*64]   = 65536  (v = att_W@q * 1/sqrt(8); legacy, unused)
#define WS_EW    139264   // [64*64]    = 4096   (f32 weights)
#define WS_EB    143360   // [64]
#define WS_M     143424   // [64*8]     = 512    (M = edge_W @ att_W)
#define WS_STATS 143936   // [B*N*2]    = 2048   (m, 1/S per node row)
#define WS_FLAG  145984   // [7] flags + 1 pad
#define WS_EWFH  145992   // [8 frag][64 lane][4 u32] bf16-hi B fragments = 4096
#define WS_EWFL  150088   // same, bf16-lo residual                      = 4096
#define WS_TOTAL 154184
// flag index: 0=edges 1=nodes 2=node_W 3=node_b 4=edge_W 5=edge_b 6=att_W

__device__ __align__(16) float g_ws[WS_TOTAL];

using short8  = __attribute__((ext_vector_type(8))) short;
using floatx4 = __attribute__((ext_vector_type(4))) float;

__device__ __forceinline__ float bf2f(uint16_t u) {
  return __uint_as_float(((uint32_t)u) << 16);
}
__device__ __forceinline__ uint16_t f2bf(float f) {   // RNE f32->bf16
  uint32_t u = __float_as_uint(f);
  return (uint16_t)((u + 0x7FFFu + ((u >> 16) & 1u)) >> 16);
}
// split two f32 into packed bf16 hi pair + bf16 residual-lo pair
__device__ __forceinline__ void split2(float f0, float f1, uint32_t& hi, uint32_t& lo) {
  uint16_t h0 = f2bf(f0), h1 = f2bf(f1);
  float r0 = f0 - bf2f(h0), r1 = f1 - bf2f(h1);
  uint16_t l0 = f2bf(r0), l1 = f2bf(r1);
  hi = (uint32_t)h0 | ((uint32_t)h1 << 16);
  lo = (uint32_t)l0 | ((uint32_t)l1 << 16);
}
__device__ __forceinline__ float load1(const void* p, size_t i, bool isf32) {
  return isf32 ? ((const float*)p)[i] : bf2f(((const uint16_t*)p)[i]);
}
__device__ __forceinline__ float elu(float x) {
  return x > 0.f ? x : expf(x) - 1.0f;
}

constexpr float INV_SQRT8 = 0.35355339059327373f;

// ------------- K0: per-array dtype detection (f32 vs bf16 in memory) -------------
__global__ __launch_bounds__(256) void k0_detect(
    const uint16_t* p0, int c0, const uint16_t* p1, int c1,
    const uint16_t* p2, int c2, const uint16_t* p3, int c3,
    const uint16_t* p4, int c4, const uint16_t* p5, int c5,
    const uint16_t* p6, int c6) {
  const uint16_t* ptrs[7] = {p0, p1, p2, p3, p4, p5, p6};
  const int cnts[7] = {c0, c1, c2, c3, c4, c5, c6};
  const int a = blockIdx.x;
  const uint16_t* e = ptrs[a];
  int S = cnts[a] / 2; if (S > 2048) S = 2048;
  const int t = threadIdx.x;
  int hi = 0, z0 = 0, nz1 = 0;
  for (int i = t; i < S; i += 256) {
    uint16_t h0 = e[2 * i], h1 = e[2 * i + 1];
    if (((h0 >> 7) & 0xFF) >= 0x90) hi++;
    if (h0 == 0) z0++;
    if (h1 != 0) nz1++;
  }
  for (int o = 32; o > 0; o >>= 1) {
    hi += __shfl_xor(hi, o); z0 += __shfl_xor(z0, o); nz1 += __shfl_xor(nz1, o);
  }
  __shared__ int r[3][4];
  if ((t & 63) == 0) { int w = t >> 6; r[0][w] = hi; r[1][w] = z0; r[2][w] = nz1; }
  __syncthreads();
  if (t == 0) {
    int H  = r[0][0] + r[0][1] + r[0][2] + r[0][3];
    int Z  = r[1][0] + r[1][1] + r[1][2] + r[1][3];
    int NZ = r[2][0] + r[2][1] + r[2][2] + r[2][3];
    g_ws[WS_FLAG + a] =
        (H > S / 16 || (Z * 8 > S * 3 && NZ * 8 > S * 3)) ? 1.0f : 0.0f;
  }
}

// ---- K1: nf, q, v (+ weight prep, distributed over block 0's four waves) ----
__global__ __launch_bounds__(256) void k1_nf_q_v(
    const void* __restrict__ nodes, const void* __restrict__ node_W,
    const void* __restrict__ node_b, const void* __restrict__ att_W,
    const void* __restrict__ edge_W, const void* __restrict__ edge_b) {
  float* nf  = g_ws + WS_NF;
  float* q   = g_ws + WS_Q;
  float* v   = g_ws + WS_V;
  float* eWf = g_ws + WS_EW;
  float* ebf = g_ws + WS_EB;
  float* Mf  = g_ws + WS_M;
  const float* fl = g_ws + WS_FLAG;
  const bool fNodes = fl[1] != 0.f, fNW = fl[2] != 0.f, fNB = fl[3] != 0.f;
  const bool fEW = fl[4] != 0.f, fEB = fl[5] != 0.f, fAW = fl[6] != 0.f;
  const int t    = threadIdx.x;
  const int lane = t & 63;
  const int wv   = t >> 6;
  const int bi   = blockIdx.x * 4 + wv;      // b*N + n
  __shared__ float nd[4][ENF];
  __shared__ float nf_s[4][FF];
  __shared__ float q_s[4][HH];
  nd[wv][lane]      = load1(nodes, (size_t)bi * ENF + lane, fNodes);
  nd[wv][lane + 64] = load1(nodes, (size_t)bi * ENF + lane + 64, fNodes);
  __syncthreads();
  float acc = load1(node_b, lane, fNB);
#pragma unroll 8
  for (int e = 0; e < ENF; ++e) acc += nd[wv][e] * load1(node_W, e * FF + lane, fNW);
  nf[bi * FF + lane] = acc;
  nf_s[wv][lane] = acc;
  __syncthreads();
  if (lane < HH) {
    float s = 0.f;
#pragma unroll
    for (int k = 0; k < FF; ++k) s += nf_s[wv][k] * load1(att_W, k * HH + lane, fAW);
    q[bi * HH + lane] = s;
    q_s[wv][lane] = s;
  }
  __syncthreads();
  {
    float s = 0.f;
#pragma unroll
    for (int h = 0; h < HH; ++h) s += load1(att_W, lane * HH + h, fAW) * q_s[wv][h];
    v[bi * FF + lane] = s * INV_SQRT8;       // fold 1/sqrt(D_EDGE)
  }
  if (blockIdx.x == 0) {                     // weight prep, one task per wave
    if (wv == 0) {
      for (int idx = lane; idx < EEF * FF; idx += 64)
        eWf[idx] = load1(edge_W, idx, fEW);
      ebf[lane] = load1(edge_b, lane, fEB);
    } else if (wv == 1) {
      // M[c][h] = sum_k edge_W[c,k] * att_W[k,h]   (lane owns row c = lane)
      float mrow[HH];
#pragma unroll
      for (int h = 0; h < HH; ++h) mrow[h] = 0.f;
      for (int k = 0; k < FF; ++k) {
        float w = load1(edge_W, (size_t)lane * FF + k, fEW);
#pragma unroll
        for (int h = 0; h < HH; ++h) mrow[h] += w * load1(att_W, k * HH + h, fAW);
      }
#pragma unroll
      for (int h = 0; h < HH; ++h) Mf[lane * HH + h] = mrow[h];
    } else {
      // pack B fragments for mfma_f32_16x16x32_bf16, split hi/lo.
      // B[k][n]: lane holds n=l&15, k=(l>>4)*8+j; frag f = ks*4+nt. wave2: ks=0, wave3: ks=1.
      const int ks = wv - 2;
      uint32_t* dH = (uint32_t*)(g_ws + WS_EWFH);
      uint32_t* dL = (uint32_t*)(g_ws + WS_EWFL);
#pragma unroll
      for (int nt = 0; nt < 4; ++nt) {
        const int f = ks * 4 + nt;
        const int n = nt * 16 + (lane & 15);
        const int e0 = ks * 32 + ((lane >> 4) << 3);
#pragma unroll
        for (int jj = 0; jj < 4; ++jj) {
          float w0 = load1(edge_W, (size_t)(e0 + 2 * jj) * FF + n, fEW);
          float w1 = load1(edge_W, (size_t)(e0 + 2 * jj + 1) * FF + n, fEW);
          uint32_t hi, lo;
          split2(w0, w1, hi, lo);
          dH[(f * 64 + lane) * 4 + jj] = hi;
          dL[(f * 64 + lane) * 4 + jj] = lo;
        }
      }
    }
  }
}

// ---------------- K2s: per-node-row softmax stats (m, 1/S) ----------------
__global__ __launch_bounds__(256) void k2_stats() {
  const float* ws_q = g_ws + WS_Q;
  float* st = g_ws + WS_STATS;
  const int bi = blockIdx.x;          // b*N + i
  const int b  = bi >> 9;
  const int t  = threadIdx.x;
  __shared__ float red[4];
  __shared__ float red2[4];
  const float* qi = ws_q + bi * HH;
  const float q0 = qi[0], q1 = qi[1], q2 = qi[2], q3 = qi[3];
  const float q4 = qi[4], q5 = qi[5], q6 = qi[6], q7 = qi[7];
  const float* qb = ws_q + ((size_t)(b << 9)) * HH;
  const int j0 = t, j1 = t + 256;
  const float* qa = qb + j0 * HH;
  float s0 = (q0*qa[0]+q1*qa[1]+q2*qa[2]+q3*qa[3]+q4*qa[4]+q5*qa[5]+q6*qa[6]+q7*qa[7]) * INV_SQRT8;
  const float* qc = qb + j1 * HH;
  float s1 = (q0*qc[0]+q1*qc[1]+q2*qc[2]+q3*qc[3]+q4*qc[4]+q5*qc[5]+q6*qc[6]+q7*qc[7]) * INV_SQRT8;
  float m = fmaxf(s0, s1);
  for (int o = 32; o > 0; o >>= 1) m = fmaxf(m, __shfl_xor(m, o));
  if ((t & 63) == 0) red[t >> 6] = m;
  __syncthreads();
  m = fmaxf(fmaxf(red[0], red[1]), fmaxf(red[2], red[3]));
  float p0 = expf(s0 - m), p1 = expf(s1 - m);
  float s = p0 + p1;
  for (int o = 32; o > 0; o >>= 1) s += __shfl_xor(s, o);
  if ((t & 63) == 0) red2[t >> 6] = s;
  __syncthreads();
  if (t == 0) {
    st[bi * 2]     = m;
    st[bi * 2 + 1] = 1.0f / (red2[0] + red2[1] + red2[2] + red2[3]);
  }
}

// ---------------- K4 combined: SINGLE edges pass, uniform dtype branch.
// 1024 threads / 16 waves, 32 rows per wave; only acc[2][4] (32 VGPR) held
// across the softmax barriers. se computed inline from the same loads
// (se = e.u + const, const cancels). B frags (split-bf16 weights) in LDS.
// f32 edges: A = split-bf16 (3 products). bf16 edges: A exact (2 products). ----------------
__global__ __launch_bounds__(1024, 1) void k4_main(
    const void* __restrict__ edges, float* __restrict__ out) {
  const bool isf32 = g_ws[WS_FLAG + 0] != 0.0f;
  const float* nf  = g_ws + WS_NF;
  const float* qws = g_ws + WS_Q;
  const float* ebf = g_ws + WS_EB;
  const float* Mf  = g_ws + WS_M;
  const float* st  = g_ws + WS_STATS;
  const int bi = blockIdx.x;          // b*N + i
  const int t  = threadIdx.x;         // 0..1023
  const int lane = t & 63;
  const int wv = t >> 6;              // wave 0..15, owns rows wv*32..wv*32+31

  __shared__ uint4 bH_s[8][64];       // B frags hi, 8KB
  __shared__ uint4 bL_s[8][64];       // B frags lo, 8KB
  __shared__ float wn_s[NN];
  __shared__ float wcol_s[NN];
  __shared__ float se_s[NN];
  __shared__ float u_s[EEF];
  __shared__ float nfi_s[FF];
  __shared__ float red[16], red2[16];
  __shared__ float aef_w[16][FF];
  __shared__ float awn_w[16][FF];

  if (t < 512) ((uint4*)bH_s)[t] = ((const uint4*)(g_ws + WS_EWFH))[t];
  else         ((uint4*)bL_s)[t - 512] = ((const uint4*)(g_ws + WS_EWFL))[t - 512];
  if (t < FF) nfi_s[t] = nf[bi * FF + t];
  if (t >= 128 && t < 128 + EEF) {
    const int c = t - 128;
    const float* qi2 = qws + bi * HH;  // uniform -> s_load
    const float* mr = Mf + c * HH;
    float s = 0.f;
#pragma unroll
    for (int h = 0; h < HH; ++h) s += mr[h] * qi2[h];
    u_s[c] = s * INV_SQRT8;            // u = (edge_W @ att_W @ q_i)/sqrt(8)
  }
  // node scores from q (symmetric sn): wn row + column
  const float m_i   = st[bi * 2];
  const float inv_i = st[bi * 2 + 1];
  const float* qi = qws + bi * HH;
  const float q0 = qi[0], q1 = qi[1], q2 = qi[2], q3 = qi[3];
  const float q4 = qi[4], q5 = qi[5], q6 = qi[6], q7 = qi[7];
  const int bbase = (bi >> 9) << 9;
  if (t < NN) {
    const float* qt = qws + ((size_t)(bbase + t)) * HH;
    const float s_t = (q0*qt[0]+q1*qt[1]+q2*qt[2]+q3*qt[3]
                      +q4*qt[4]+q5*qt[5]+q6*qt[6]+q7*qt[7]) * INV_SQRT8;
    wn_s[t] = expf(s_t - m_i) * inv_i;                  // wn[i, t]
    const float2 stt = ((const float2*)st)[bbase + t];
    wcol_s[t] = expf(s_t - stt.x) * stt.y;              // wn[t, i]
  }
  __syncthreads();                                      // B0

  // ---- single pass: load rows once; inline score + MFMA into acc[2][4] ----
  // A[i][k]: lane holds i=lane&15, k=(lane>>4)*8+j. C: col=lane&15, row=(lane>>4)*4+r.
  float eb_n[4], nf_v[4];
#pragma unroll
  for (int nt = 0; nt < 4; ++nt) {
    eb_n[nt] = ebf[nt * 16 + (lane & 15)];
    nf_v[nt] = nfi_s[nt * 16 + (lane & 15)];
  }
  const int g8 = (lane >> 4) << 3;    // this lane's k-base (0,8,16,24)
  float ulo[8], uhi[8];
#pragma unroll
  for (int j = 0; j < 8; ++j) { ulo[j] = u_s[g8 + j]; uhi[j] = u_s[g8 + 32 + j]; }

  floatx4 acc[2][4];
  if (isf32) {
    const float* ef32 = (const float*)edges + ((size_t)bi * NN + wv * 32) * EEF;
#pragma unroll
    for (int mt = 0; mt < 2; ++mt) {
      const float* ap = ef32 + (size_t)(mt * 16 + (lane & 15)) * EEF + g8;
      const float4 x0 = *(const float4*)(ap);
      const float4 x1 = *(const float4*)(ap + 4);
      const float4 x2 = *(const float4*)(ap + 32);
      const float4 x3 = *(const float4*)(ap + 36);
      // inline edge score partial (f32): se_row = e_row . u  (+const, cancels)
      float p = x0.x*ulo[0] + x0.y*ulo[1] + x0.z*ulo[2] + x0.w*ulo[3]
              + x1.x*ulo[4] + x1.y*ulo[5] + x1.z*ulo[6] + x1.w*ulo[7]
              + x2.x*uhi[0] + x2.y*uhi[1] + x2.z*uhi[2] + x2.w*uhi[3]
              + x3.x*uhi[4] + x3.y*uhi[5] + x3.z*uhi[6] + x3.w*uhi[7];
      p += __shfl_xor(p, 16);
      p += __shfl_xor(p, 32);
      if (lane < 16) se_s[wv * 32 + mt * 16 + lane] = p;
      // convert to split-bf16 A fragments (k 0..31 -> a0, k 32..63 -> a1)
      union { uint32_t u[4]; short8 s; } a0h, a0l, a1h, a1l;
      split2(x0.x, x0.y, a0h.u[0], a0l.u[0]);
      split2(x0.z, x0.w, a0h.u[1], a0l.u[1]);
      split2(x1.x, x1.y, a0h.u[2], a0l.u[2]);
      split2(x1.z, x1.w, a0h.u[3], a0l.u[3]);
      split2(x2.x, x2.y, a1h.u[0], a1l.u[0]);
      split2(x2.z, x2.w, a1h.u[1], a1l.u[1]);
      split2(x3.x, x3.y, a1h.u[2], a1l.u[2]);
      split2(x3.z, x3.w, a1h.u[3], a1l.u[3]);
#pragma unroll
      for (int nt = 0; nt < 4; ++nt) {
        const uint4 h0 = bH_s[nt][lane];
        const uint4 h1 = bH_s[4 + nt][lane];
        const uint4 l0 = bL_s[nt][lane];
        const uint4 l1 = bL_s[4 + nt][lane];
        floatx4 c = (floatx4){eb_n[nt], eb_n[nt], eb_n[nt], eb_n[nt]};
        c = __builtin_amdgcn_mfma_f32_16x16x32_bf16(a0h.s, *(const short8*)&h0, c, 0, 0, 0);
        c = __builtin_amdgcn_mfma_f32_16x16x32_bf16(a1h.s, *(const short8*)&h1, c, 0, 0, 0);
        c = __builtin_amdgcn_mfma_f32_16x16x32_bf16(a0h.s, *(const short8*)&l0, c, 0, 0, 0);
        c = __builtin_amdgcn_mfma_f32_16x16x32_bf16(a1h.s, *(const short8*)&l1, c, 0, 0, 0);
        c = __builtin_amdgcn_mfma_f32_16x16x32_bf16(a0l.s, *(const short8*)&h0, c, 0, 0, 0);
        c = __builtin_amdgcn_mfma_f32_16x16x32_bf16(a1l.s, *(const short8*)&h1, c, 0, 0, 0);
        acc[mt][nt] = c;
      }
    }
  } else {
    // bf16 edges: A fragments are exact; C = A*(Bh + Bl), 2 products per half-k.
    const uint16_t* eb16 = (const uint16_t*)edges + ((size_t)bi * NN + wv * 32) * EEF;
#pragma unroll
    for (int mt = 0; mt < 2; ++mt) {
      const uint16_t* ap = eb16 + (size_t)(mt * 16 + (lane & 15)) * EEF + g8;
      const short8 a0 = *(const short8*)(ap);
      const short8 a1 = *(const short8*)(ap + 32);
      // inline edge score partial
      float p = 0.f;
#pragma unroll
      for (int j = 0; j < 8; ++j) {
        p += bf2f((uint16_t)a0[j]) * ulo[j];
        p += bf2f((uint16_t)a1[j]) * uhi[j];
      }
      p += __shfl_xor(p, 16);
      p += __shfl_xor(p, 32);
      if (lane < 16) se_s[wv * 32 + mt * 16 + lane] = p;
#pragma unroll
      for (int nt = 0; nt < 4; ++nt) {
        const uint4 h0 = bH_s[nt][lane];
        const uint4 h1 = bH_s[4 + nt][lane];
        const uint4 l0 = bL_s[nt][lane];
        const uint4 l1 = bL_s[4 + nt][lane];
        floatx4 c = (floatx4){eb_n[nt], eb_n[nt], eb_n[nt], eb_n[nt]};
        c = __builtin_amdgcn_mfma_f32_16x16x32_bf16(a0, *(const short8*)&h0, c, 0, 0, 0);
        c = __builtin_amdgcn_mfma_f32_16x16x32_bf16(a1, *(const short8*)&h1, c, 0, 0, 0);
        c = __builtin_amdgcn_mfma_f32_16x16x32_bf16(a0, *(const short8*)&l0, c, 0, 0, 0);
        c = __builtin_amdgcn_mfma_f32_16x16x32_bf16(a1, *(const short8*)&l1, c, 0, 0, 0);
        acc[mt][nt] = c;
      }
    }
  }
  __syncthreads();                                      // B1

  // ---- softmax over 512 rows (threads t<512 own one row each) ----
  const float sev = (t < NN) ? se_s[t] : -3.0e38f;
  float m = sev;
  for (int o = 32; o > 0; o >>= 1) m = fmaxf(m, __shfl_xor(m, o));
  if (lane == 0) red[wv] = m;
  __syncthreads();                                      // B2
  m = red[0];
#pragma unroll
  for (int w = 1; w < 16; ++w) m = fmaxf(m, red[w]);
  const float p = (t < NN) ? expf(sev - m) : 0.f;
  float ssum = p;
  for (int o = 32; o > 0; o >>= 1) ssum += __shfl_xor(ssum, o);
  if (lane == 0) red2[wv] = ssum;
  if (t < NN) se_s[t] = p;
  __syncthreads();                                      // B2b
  float tot = red2[0];
#pragma unroll
  for (int w = 1; w < 16; ++w) tot += red2[w];
  const float inv_tot = 1.0f / tot;

  // ---- epilogue from held accumulators ----
  float aef_v[4] = {0.f, 0.f, 0.f, 0.f};
  float* oute = out + 65536 + ((size_t)bi * NN + wv * 32) * EEF;
#pragma unroll
  for (int mt = 0; mt < 2; ++mt) {
#pragma unroll
    for (int r = 0; r < 4; ++r) {
      const int row = mt * 16 + ((lane >> 4) << 2) + r;
      const float we = se_s[wv * 32 + row] * inv_tot;
      const float wnr = wn_s[wv * 32 + row];
      const float onewe = 1.0f + we;
#pragma unroll
      for (int nt = 0; nt < 4; ++nt) {
        const float c = acc[mt][nt][r];
        oute[(size_t)row * EEF + nt * 16 + (lane & 15)] = elu(c * onewe + wnr * nf_v[nt]);
        aef_v[nt] = fmaf(we, c, aef_v[nt]);
      }
    }
  }
#pragma unroll
  for (int nt = 0; nt < 4; ++nt) {
    float g = aef_v[nt];
    g += __shfl_xor(g, 16);
    g += __shfl_xor(g, 32);
    if (lane < 16) aef_w[wv][nt * 16 + lane] = g;
  }

  // ---- awn[b,i,k] = sum_j wn[b,j,i]*nf[b,j,k]  (32 j's per wave) ----
  float awn_acc = 0.f;
  {
    const float* nfb = nf + (size_t)bbase * FF;
#pragma unroll 8
    for (int jj = 0; jj < 32; ++jj) {
      const int j = wv * 32 + jj;
      awn_acc = fmaf(wcol_s[j], nfb[(size_t)j * FF + lane], awn_acc);
    }
  }
  awn_w[wv][lane] = awn_acc;
  __syncthreads();                                      // B3

  if (t < FF) {
    float sum = nfi_s[t];
#pragma unroll
    for (int w = 0; w < 16; ++w) sum += aef_w[w][t] + awn_w[w][t];
    out[bi * FF + t] = elu(sum);
  }
}

extern "C" void kernel_launch(void* const* d_in, const int* in_sizes, int n_in,
                              void* d_out, int out_size, void* d_ws, size_t ws_size,
                              hipStream_t stream) {
  // Identify inputs by element count (robust to mask-dropping / reordering).
  const void* nodes = nullptr; const void* edges = nullptr;
  const void* node_W = nullptr; const void* node_b = nullptr;
  const void* edge_W = nullptr; const void* edge_b = nullptr;
  const void* att_W = nullptr;
  int bias_seen = 0;
  for (int i = 0; i < n_in; ++i) {
    switch (in_sizes[i]) {
      case 33554432: edges  = d_in[i]; break;
      case 131072:   nodes  = d_in[i]; break;
      case 8192:     node_W = d_in[i]; break;
      case 4096:     edge_W = d_in[i]; break;
      case 512:      att_W  = d_in[i]; break;
      case 64:       if (bias_seen++ == 0) node_b = d_in[i]; else edge_b = d_in[i]; break;
      default: break;  // mask or scalars: unused
    }
  }
  float* out = (float*)d_out;

  k0_detect<<<dim3(7), dim3(256), 0, stream>>>(
      (const uint16_t*)edges, 33554432, (const uint16_t*)nodes, 131072,
      (const uint16_t*)node_W, 8192, (const uint16_t*)node_b, 64,
      (const uint16_t*)edge_W, 4096, (const uint16_t*)edge_b, 64,
      (const uint16_t*)att_W, 512);
  k1_nf_q_v<<<dim3(BB * NN / 4), dim3(256), 0, stream>>>(nodes, node_W, node_b,
                                                         att_W, edge_W, edge_b);
  k2_stats<<<dim3(BB * NN), dim3(256), 0, stream>>>();
  k4_main<<<dim3(BB * NN), dim3(1024), 0, stream>>>(edges, out);
}